// Round 4
// baseline (609.752 us; speedup 1.0000x reference)
//
#include <hip/hip_runtime.h>

typedef _Float16 f16;
typedef __attribute__((ext_vector_type(4))) _Float16 f16x4;
typedef __attribute__((ext_vector_type(8))) _Float16 f16x8;
typedef __attribute__((ext_vector_type(4))) float f32x4;
typedef __attribute__((ext_vector_type(2))) unsigned int u32x2;
typedef __attribute__((ext_vector_type(4))) unsigned int u32x4;

#define BB 8
#define SS 1024
#define DD 1024
#define HH 16
#define HD 64
#define QPB 16
#define PROW 1032   // Pf/Tf row stride (f16): 516 dw === 4 mod 8 -> ~2-way banks max
#define TSTR 520    // fallback kernel strides
#define KSTR 72
#define RVF 1024    // Rvful global row stride (f16)

#define VT_ELEMS  ((size_t)BB * HH * HD * SS)   // 8,388,608
#define RVF_ELEMS ((size_t)HD * RVF)            // 65,536
#define RKF_ELEMS ((size_t)SS * HD)             // 65,536
#define KT_ELEMS  ((size_t)BB * HH * SS * HD)   // 8,388,608
#define WS_PART ((VT_ELEMS + RVF_ELEMS + RKF_ELEMS) * 2)
#define WS_FULL ((VT_ELEMS + RVF_ELEMS + RKF_ELEMS + KT_ELEMS) * 2)

__device__ inline f16x8 cvt16(float4 a, float4 b) {
  f16x8 h;
  h[0] = (f16)a.x; h[1] = (f16)a.y; h[2] = (f16)a.z; h[3] = (f16)a.w;
  h[4] = (f16)b.x; h[5] = (f16)b.y; h[6] = (f16)b.z; h[7] = (f16)b.w;
  return h;
}

// funnel-extract 8 f16 starting at element s (0..7) of a 16-f16 window {lo, hi}
// sh = s>>1, lob = (s&1)*16
__device__ inline f16x8 funnel8(u32x4 lo, u32x4 hi, int sh, unsigned lob) {
  unsigned e0 = (sh & 1) ? lo.y : lo.x;
  unsigned e1 = (sh & 1) ? lo.z : lo.y;
  unsigned e2 = (sh & 1) ? lo.w : lo.z;
  unsigned e3 = (sh & 1) ? hi.x : lo.w;
  unsigned e4 = (sh & 1) ? hi.y : hi.x;
  unsigned f0 = (sh & 2) ? e2 : e0;
  unsigned f1 = (sh & 2) ? e3 : e1;
  unsigned f2 = (sh & 2) ? e4 : e2;
  unsigned f3 = (sh & 2) ? ((sh & 1) ? hi.z : hi.y) : e3;
  unsigned f4 = (sh & 2) ? ((sh & 1) ? hi.w : hi.z) : e4;
  union { u32x4 u; f16x8 h; } o;
  o.u.x = __builtin_amdgcn_alignbit(f1, f0, lob);
  o.u.y = __builtin_amdgcn_alignbit(f2, f1, lob);
  o.u.z = __builtin_amdgcn_alignbit(f3, f2, lob);
  o.u.w = __builtin_amdgcn_alignbit(f4, f3, lob);
  return o.h;
}

// ---- prep: Vt[b][h][d][s], Rvful[d][j] (palindromic transpose), Rkful[j][d]
//      (palindromic cast), Kt[b][h][s][d] f16 cast ----
__global__ __launch_bounds__(256, 2)
void prep_kernel(const float* __restrict__ Vg, const float* __restrict__ Rvg,
                 const float* __restrict__ Kg, const float* __restrict__ Rkg,
                 f16* __restrict__ Vt, f16* __restrict__ Rvf,
                 f16* __restrict__ Rkf, f16* __restrict__ Kt) {
  __shared__ __align__(16) f16 Tt[64 * KSTR];
  const int tid = threadIdx.x;
  const int bid = blockIdx.x;

  if (bid < 2056) {  // transpose sections (V, Rv)
    const int sr = tid >> 2, cs = (tid & 3) * 16;
    const float* src;
    int srcstride;
    f16* dst;
    int dststride, dstcol;
    if (bid < 2048) {
      int b = bid >> 8, h = (bid >> 4) & 15, tc = bid & 15;
      src = Vg + ((size_t)(b * SS + tc * 64)) * DD + h * HD;
      srcstride = DD;
      dst = Vt + ((size_t)((b * HH + h) * HD)) * SS;
      dststride = SS; dstcol = tc * 64;
    } else {
      int cc = bid - 2048;                       // 0..7, dists 0..511
      src = Rvg + ((size_t)(cc * 64)) * HD;
      srcstride = HD;
      dst = Rvf;
      dststride = RVF; dstcol = cc * 64;
    }
    {
      const float* s = src + (size_t)sr * srcstride + cs;
      float4 v0 = *(const float4*)(s);
      float4 v1 = *(const float4*)(s + 4);
      float4 v2 = *(const float4*)(s + 8);
      float4 v3 = *(const float4*)(s + 12);
      *(f16x8*)(Tt + sr * KSTR + cs) = cvt16(v0, v1);
      *(f16x8*)(Tt + sr * KSTR + cs + 8) = cvt16(v2, v3);
    }
    __syncthreads();
    {
      f16x8 o0, o1;
      #pragma unroll
      for (int i = 0; i < 8; ++i) o0[i] = Tt[(cs + i) * KSTR + sr];
      #pragma unroll
      for (int i = 0; i < 8; ++i) o1[i] = Tt[(cs + 8 + i) * KSTR + sr];
      f16* o = dst + (size_t)sr * dststride + dstcol + cs;
      *(f16x8*)(o) = o0;
      *(f16x8*)(o + 8) = o1;
      if (bid >= 2048) {  // Rv palindromic mirror: col (1024 - dist) for dist 1..511
        #pragma unroll
        for (int i = 0; i < 8; ++i) {
          int dist = dstcol + cs + i;
          if (dist > 0) dst[(size_t)sr * dststride + (1024 - dist)] = o0[i];
        }
        #pragma unroll
        for (int i = 0; i < 8; ++i) {
          int dist = dstcol + cs + 8 + i;
          dst[(size_t)sr * dststride + (1024 - dist)] = o1[i];
        }
      }
    }
  } else if (bid < 2060) {  // Rkful: rows j = 0..1023 from Rkg[min(j,1024-j)]
    const int jrow = (bid - 2056) * 256 + tid;
    const int srcr = (jrow <= 512) ? jrow : (1024 - jrow);
    const float* s = Rkg + (size_t)srcr * HD;
    f16* o = Rkf + (size_t)jrow * HD;
    #pragma unroll
    for (int c8 = 0; c8 < 8; ++c8) {
      float4 a = *(const float4*)(s + c8 * 8);
      float4 b2 = *(const float4*)(s + c8 * 8 + 4);
      *(f16x8*)(o + c8 * 8) = cvt16(a, b2);
    }
    if (bid == 2056 && tid < 64)   // Rvful col j=512 (dist 512, not in transpose range)
      Rvf[(size_t)tid * RVF + 512] = (f16)Rvg[512 * HD + tid];
  } else {
    // K cast -> Kt[b][h][s][d]
    const int n = bid - 2060;
    #pragma unroll
    for (int jj = 0; jj < 4; ++jj) {
      int o4 = n * 1024 + jj * 256 + tid;
      int d4 = o4 & 15;
      int s  = (o4 >> 4) & 1023;
      int bh = o4 >> 14;                 // 0..127
      int b = bh >> 4, h = bh & 15;
      float4 v = *(const float4*)(Kg + ((size_t)(b * SS + s)) * DD + h * HD + d4 * 4);
      f16x4 hv; hv[0] = (f16)v.x; hv[1] = (f16)v.y; hv[2] = (f16)v.z; hv[3] = (f16)v.w;
      *(f16x4*)(Kt + (size_t)o4 * 4) = hv;
    }
  }
}

// ---- main v8b: palindromic-table formulation (v8 + race fix).
// Tf[q][j] = Q . Rkful^T; Phase A bias = aligned b64-pair + funnel; Phase W DELETED
// (rel_v = plain GEMM vs Rvful with per-row-shifted P reads); stride 1032.
// RACE FIX vs v8: partial-co staging goes through Tf (dead after Phase A, barrier-2
// ordered), NOT Pf (still being read by slower waves in Phase B+Wful).
template <bool KT16>
__global__ __launch_bounds__(512, 4)
void circ_attn_v8(const float* __restrict__ Qg, const float* __restrict__ Kg,
                  const f16* __restrict__ Kt, const f16* __restrict__ Rkf,
                  const f16* __restrict__ Vt, const f16* __restrict__ Rvf,
                  float* __restrict__ Out) {
  __shared__ __align__(16) f16 Pf[QPB * PROW];
  __shared__ __align__(16) f16 Tf[QPB * PROW];
  __shared__ float lsw[8][16];

  // XCD swizzle: all 64 q-blocks of one (b,h) land on XCD (g & 7)
  const int i = blockIdx.x;
  const int g = ((i >> 9) << 3) | (i & 7);   // (b,h) group 0..127
  const int m = (i >> 3) & 63;               // q-block 0..63
  const int b = g >> 4;
  const int h = g & 15;
  const int q0 = m * QPB;

  const int tid = threadIdx.x;
  const int w = tid >> 6;        // 0..7
  const int lane = tid & 63;
  const int quad = lane >> 4;
  const int l16 = lane & 15;
  const int wd = w & 3;          // output d-group 0..3
  const int wh = w >> 2;         // k-half / j-half 0..1

  // ---- Q fragments straight from global (A-layout == B-layout) ----
  f16x8 qf0, qf1;
  {
    const float* qrow = Qg + ((size_t)(b * SS + q0 + l16)) * DD + h * HD;
    float4 a0 = *(const float4*)(qrow + quad * 8);
    float4 a1 = *(const float4*)(qrow + quad * 8 + 4);
    float4 a2 = *(const float4*)(qrow + 32 + quad * 8);
    float4 a3 = *(const float4*)(qrow + 32 + quad * 8 + 4);
    qf0 = cvt16(a0, a1);
    qf1 = cvt16(a2, a3);
  }

  // ---- Phase T: Tf[q][j] = Q . Rkful^T, vectorized writes (A=Rkf rows -> j rows,
  //      B=Q -> q cols; c[r] = T[q=l16][j = cc*128 + w*16 + quad*4 + r]) ----
  {
    const f16* rkp = Rkf + ((size_t)(w * 16 + l16)) * HD + quad * 8;
    f16x8 t0 = *(const f16x8*)(rkp);
    f16x8 t1 = *(const f16x8*)(rkp + 32);
    #pragma unroll
    for (int cc = 0; cc < 8; ++cc) {
      f16x8 c0 = t0, c1 = t1;
      if (cc < 7) {
        const f16* np = rkp + (size_t)(cc + 1) * 128 * HD;
        t0 = *(const f16x8*)(np);
        t1 = *(const f16x8*)(np + 32);
      }
      f32x4 c = {0.f, 0.f, 0.f, 0.f};
      c = __builtin_amdgcn_mfma_f32_16x16x32_f16(c0, qf0, c, 0, 0, 0);
      c = __builtin_amdgcn_mfma_f32_16x16x32_f16(c1, qf1, c, 0, 0, 0);
      f16x4 tw;
      #pragma unroll
      for (int r = 0; r < 4; ++r) tw[r] = (f16)c[r];
      *(f16x4*)(Tf + l16 * PROW + cc * 128 + w * 16 + quad * 4) = tw;
    }
  }
  // pad Tf cols 1024..1031: copy cols 0..7 (written by wave 0)
  if (w == 0 && lane < 16)
    *(f16x8*)(Tf + lane * PROW + 1024) = *(const f16x8*)(Tf + lane * PROW);

  // Phase A initial K prefetch (independent of Tf, issued before barrier 1)
  const f16* kp16 = KT16 ?
      (Kt + (((size_t)(b * HH + h) << 10) + w * 16 + l16) * HD + quad * 8) : nullptr;
  const float* kp32 = KT16 ? nullptr :
      (Kg + ((size_t)(b * SS + w * 16 + l16)) * DD + h * HD + quad * 8);
  f16x8 ka0, ka1, kb0, kb1;
  float4 f0, f1, f2, f3;
  if (KT16) {
    ka0 = *(const f16x8*)(kp16);
    ka1 = *(const f16x8*)(kp16 + 32);
    kb0 = *(const f16x8*)(kp16 + 128 * HD);
    kb1 = *(const f16x8*)(kp16 + 128 * HD + 32);
  } else {
    f0 = *(const float4*)(kp32);
    f1 = *(const float4*)(kp32 + 4);
    f2 = *(const float4*)(kp32 + 32);
    f3 = *(const float4*)(kp32 + 36);
  }
  __syncthreads();   // barrier 1: Tf ready

  // ---- Phase A: S^T = K . Q^T ; bias via aligned b64-pair + funnel from Tf ----
  {
    float psum = 0.f;
    #pragma unroll
    for (int kc = 0; kc < 8; ++kc) {
      f16x8 c0, c1;
      if (KT16) {
        c0 = ka0; c1 = ka1; ka0 = kb0; ka1 = kb1;
        if (kc < 6) {
          const f16* np = kp16 + (size_t)(kc + 2) * 128 * HD;
          kb0 = *(const f16x8*)(np);
          kb1 = *(const f16x8*)(np + 32);
        }
      } else {
        c0 = cvt16(f0, f1); c1 = cvt16(f2, f3);
        if (kc < 7) {
          const float* s = kp32 + (size_t)(kc + 1) * 128 * DD;
          f0 = *(const float4*)(s);      f1 = *(const float4*)(s + 4);
          f2 = *(const float4*)(s + 32); f3 = *(const float4*)(s + 36);
        }
      }
      const int kb_ = kc * 128 + w * 16 + quad * 4;
      const int qg = q0 + l16;
      const int j0 = (qg - kb_) & 1023;          // bias col for r=0
      const int jm = (j0 - 3) & 1023;            // window start (r=3)
      const int a0 = jm & ~3;
      const f16* tp = Tf + l16 * PROW + a0;
      u32x2 lo = *(const u32x2*)(tp);
      u32x2 hi = *(const u32x2*)(tp + 4);
      const int s4 = jm & 3;
      unsigned D0 = lo.x, D1 = lo.y, D2 = hi.x, D3 = hi.y;
      unsigned A0 = (s4 & 2) ? D1 : D0;
      unsigned A1 = (s4 & 2) ? D2 : D1;
      unsigned A2 = (s4 & 2) ? D3 : D2;
      unsigned lob = (unsigned)((s4 & 1) * 16);
      union { u32x2 u; f16x4 hh; } tw;
      tw.u.x = __builtin_amdgcn_alignbit(A1, A0, lob);
      tw.u.y = __builtin_amdgcn_alignbit(A2, A1, lob);
      // tw.hh[t] = Tf[q][jm + t]; r-th value at j = j0 - r = jm + 3 - r
      f32x4 c = {0.f, 0.f, 0.f, 0.f};
      c = __builtin_amdgcn_mfma_f32_16x16x32_f16(c0, qf0, c, 0, 0, 0);
      c = __builtin_amdgcn_mfma_f32_16x16x32_f16(c1, qf1, c, 0, 0, 0);
      f16x4 pv;
      #pragma unroll
      for (int r = 0; r < 4; ++r) {
        float sc = fmaf(c[r], 0.125f, (float)tw.hh[3 - r]);
        float p = __expf(sc);           // no max-subtract: |sc| small, fp32-safe
        pv[r] = (f16)p;
        psum += p;
      }
      *(f16x4*)(Pf + l16 * PROW + kb_) = pv;
    }
    psum += __shfl_xor(psum, 16);
    psum += __shfl_xor(psum, 32);
    if (quad == 0) lsw[w][l16] = psum;
  }
  // circular pad: Pf[q][1024..1031] = Pf[q][0..7] (wave 0 wrote cols 0..7 at kc=0)
  if (w == 0 && lane < 16)
    *(f16x8*)(Pf + lane * PROW + 1024) = *(const f16x8*)(Pf + lane * PROW);

  // B+Wful prefetch (independent of Pf): V and Rvful streams, 2-deep
  const f16* vtp = Vt + ((size_t)((b * HH + h) * HD) + wd * 16 + l16) * SS
                      + wh * 512 + quad * 8;
  const f16* rvp = Rvf + ((size_t)(wd * 16 + l16)) * RVF + wh * 512 + quad * 8;
  f16x8 va0 = *(const f16x8*)(vtp);
  f16x8 va1 = *(const f16x8*)(vtp + 32);
  f16x8 vb0 = *(const f16x8*)(vtp + 64);
  f16x8 vb1 = *(const f16x8*)(vtp + 96);
  f16x8 ra0 = *(const f16x8*)(rvp);
  f16x8 ra1 = *(const f16x8*)(rvp + 32);
  f16x8 rb0 = *(const f16x8*)(rvp + 64);
  f16x8 rb1 = *(const f16x8*)(rvp + 96);
  __syncthreads();   // barrier 2: Pf + pad + lsw ready; Tf now DEAD (reusable)

  // ---- Phase B+Wful: co = P.V + Pshift.Rvful ; wave (wd,wh) = d-group x half ----
  f32x4 co = {0.f, 0.f, 0.f, 0.f};
  {
    #pragma unroll
    for (int kc = 0; kc < 8; ++kc) {
      f16x8 cv0 = va0, cv1 = va1, cr0 = ra0, cr1 = ra1;
      va0 = vb0; va1 = vb1; ra0 = rb0; ra1 = rb1;
      if (kc < 6) {
        vb0 = *(const f16x8*)(vtp + (kc + 2) * 64);
        vb1 = *(const f16x8*)(vtp + (kc + 2) * 64 + 32);
        rb0 = *(const f16x8*)(rvp + (kc + 2) * 64);
        rb1 = *(const f16x8*)(rvp + (kc + 2) * 64 + 32);
      }
      // P . V  (A = P rows q, k-block wh*512 + kc*64)
      const int jb = wh * 512 + kc * 64 + quad * 8;
      f16x8 ap0 = *(const f16x8*)(Pf + l16 * PROW + jb);
      f16x8 ap1 = *(const f16x8*)(Pf + l16 * PROW + jb + 32);
      co = __builtin_amdgcn_mfma_f32_16x16x32_f16(ap0, cv0, co, 0, 0, 0);
      co = __builtin_amdgcn_mfma_f32_16x16x32_f16(ap1, cv1, co, 0, 0, 0);
      // Pshift . Rvful  (A row q reads P[q][(q + j) & 1023] -- per-row shift, funnel)
      const int s0 = (q0 + l16 + jb) & 1023;
      const int b16 = s0 & ~7;
      const int sh = s0 & 7;
      const unsigned lob = (unsigned)((sh & 1) * 16);
      const f16* pp0 = Pf + l16 * PROW + b16;
      u32x4 W0 = *(const u32x4*)(pp0);
      u32x4 W1 = *(const u32x4*)(pp0 + 8);
      f16x8 aw0 = funnel8(W0, W1, sh >> 1, lob);
      const int b16b = (b16 + 32) & 1023;        // (s0+32) keeps the same sh
      const f16* pp1 = Pf + l16 * PROW + b16b;
      u32x4 X0 = *(const u32x4*)(pp1);
      u32x4 X1 = *(const u32x4*)(pp1 + 8);
      f16x8 aw1 = funnel8(X0, X1, sh >> 1, lob);
      co = __builtin_amdgcn_mfma_f32_16x16x32_f16(aw0, cr0, co, 0, 0, 0);
      co = __builtin_amdgcn_mfma_f32_16x16x32_f16(aw1, cr1, co, 0, 0, 0);
    }
  }

  // ---- pairwise partial-sum reduction through Tf (dead since barrier 2) ----
  if (w >= 4)
    *(f32x4*)((float*)Tf + ((size_t)(wd * 64 + lane)) * 4) = co;
  __syncthreads();   // barrier 3: partials staged (all waves past Phase B reads of Pf)
  if (w < 4) {
    f32x4 part = *(const f32x4*)((const float*)Tf + ((size_t)(w * 64 + lane)) * 4);
    co += part;
    // ---- finalize: normalize + store (no dist-512 specials -- j=512 is in Wful) ----
    const int d = w * 16 + l16;
    #pragma unroll
    for (int r = 0; r < 4; ++r) {
      int ql = quad * 4 + r;
      float l = 0.f;
      #pragma unroll
      for (int j = 0; j < 8; ++j) l += lsw[j][ql];
      Out[((size_t)(b * SS + q0 + ql)) * DD + h * HD + d] = co[r] / l;
    }
  }
}

// ---- fallback (R2-style, used only if ws_size is tiny) ----
#define FPSTR 1032
#define FVSTR 68
__global__ __launch_bounds__(256, 2)
void circ_attn_mfma(const float* __restrict__ Qg, const float* __restrict__ Kg,
                    const float* __restrict__ Vg, const float* __restrict__ Rkg,
                    const float* __restrict__ Rvg, float* __restrict__ Out) {
  __shared__ __align__(16) f16 Pf[QPB * FPSTR];
  __shared__ __align__(16) f16 Tb[QPB * TSTR];
  __shared__ __align__(16) f16 Sb[64 * KSTR];
  __shared__ __align__(16) f16 Qb[QPB * KSTR];
  __shared__ float lsw[4][16];
  const int bid = blockIdx.x;
  const int b = bid >> 10, h = (bid >> 6) & 15, q0 = (bid & 63) * QPB;
  const int tid = threadIdx.x, w = tid >> 6, lane = tid & 63;
  const int quad = lane >> 4, l16 = lane & 15;
  auto stage64 = [&](const float* src, int rstride, f16* dst, int dstr) {
    #pragma unroll
    for (int jj = 0; jj < 4; ++jj) {
      int i = jj * 256 + tid;
      int r = i >> 4, c = (i & 15) << 2;
      float4 v = *(const float4*)(src + (size_t)r * rstride + c);
      f16x4 hv; hv[0] = (f16)v.x; hv[1] = (f16)v.y; hv[2] = (f16)v.z; hv[3] = (f16)v.w;
      *(f16x4*)(dst + r * dstr + c) = hv;
    }
  };
  {
    int r = tid >> 4, c = (tid & 15) << 2;
    float4 v = *(const float4*)(Qg + (size_t)(b * SS + q0 + r) * DD + h * HD + c);
    f16x4 hv; hv[0] = (f16)v.x; hv[1] = (f16)v.y; hv[2] = (f16)v.z; hv[3] = (f16)v.w;
    *(f16x4*)(Qb + r * KSTR + c) = hv;
  }
  __syncthreads();
  const f16x8 qf0 = *(const f16x8*)(Qb + l16 * KSTR + quad * 8);
  const f16x8 qf1 = *(const f16x8*)(Qb + l16 * KSTR + 32 + quad * 8);
  #pragma unroll 1
  for (int cc = 0; cc < 8; ++cc) {
    stage64(Rkg + (size_t)(cc * 64) * HD, HD, Sb, KSTR);
    __syncthreads();
    f16x8 rk0 = *(const f16x8*)(Sb + (w * 16 + l16) * KSTR + quad * 8);
    f16x8 rk1 = *(const f16x8*)(Sb + (w * 16 + l16) * KSTR + 32 + quad * 8);
    f32x4 c = {0.f, 0.f, 0.f, 0.f};
    c = __builtin_amdgcn_mfma_f32_16x16x32_f16(qf0, rk0, c, 0, 0, 0);
    c = __builtin_amdgcn_mfma_f32_16x16x32_f16(qf1, rk1, c, 0, 0, 0);
    const int dbase = cc * 64 + w * 16 + l16;
    #pragma unroll
    for (int r = 0; r < 4; ++r) Tb[(quad * 4 + r) * TSTR + dbase] = (f16)c[r];
    __syncthreads();
  }
  if (w == 0) {
    float t = 0.f;
    #pragma unroll
    for (int i = 0; i < 16; ++i)
      t += (float)Qb[l16 * KSTR + quad * 16 + i] * Rkg[512 * HD + quad * 16 + i];
    t += __shfl_xor(t, 16); t += __shfl_xor(t, 32);
    if (quad == 0) Tb[l16 * TSTR + 512] = (f16)t;
  }
  float psum = 0.f;
  #pragma unroll 1
  for (int kc = 0; kc < 16; ++kc) {
    stage64(Kg + (size_t)(b * SS + kc * 64) * DD + h * HD, DD, Sb, KSTR);
    __syncthreads();
    f16x8 ka0 = *(const f16x8*)(Sb + (w * 16 + l16) * KSTR + quad * 8);
    f16x8 ka1 = *(const f16x8*)(Sb + (w * 16 + l16) * KSTR + 32 + quad * 8);
    f32x4 c = {0.f, 0.f, 0.f, 0.f};
    c = __builtin_amdgcn_mfma_f32_16x16x32_f16(ka0, qf0, c, 0, 0, 0);
    c = __builtin_amdgcn_mfma_f32_16x16x32_f16(ka1, qf1, c, 0, 0, 0);
    const int kb = kc * 64 + w * 16 + quad * 4;
    const int q = q0 + l16;
    f16x4 pv;
    #pragma unroll
    for (int r = 0; r < 4; ++r) {
      int key = kb + r;
      int j = (q - key) & 1023;
      int dist = (j < 1024 - j) ? j : 1024 - j;
      float s = c[r] * 0.125f + (float)Tb[l16 * TSTR + dist];
      float p = __expf(s);
      pv[r] = (f16)p;
      psum += p;
    }
    *(f16x4*)(Pf + l16 * FPSTR + kb) = pv;
    __syncthreads();
  }
  psum += __shfl_xor(psum, 16); psum += __shfl_xor(psum, 32);
  if (quad == 0) lsw[w][l16] = psum;
  f32x4 co = {0.f, 0.f, 0.f, 0.f};
  const int d = w * 16 + l16;
  #pragma unroll 1
  for (int kc = 0; kc < 16; ++kc) {
    stage64(Vg + (size_t)(b * SS + kc * 64) * DD + h * HD, DD, Sb, FVSTR);
    __syncthreads();
    #pragma unroll
    for (int kd = 0; kd < 2; ++kd) {
      f16x8 bv;
      #pragma unroll
      for (int j = 0; j < 8; ++j) bv[j] = Sb[(kd * 32 + quad * 8 + j) * FVSTR + d];
      f16x8 ap = *(const f16x8*)(Pf + l16 * FPSTR + kc * 64 + kd * 32 + quad * 8);
      co = __builtin_amdgcn_mfma_f32_16x16x32_f16(ap, bv, co, 0, 0, 0);
    }
    __syncthreads();
  }
  #pragma unroll 1
  for (int i = tid; i < QPB * 513; i += 256) {
    int ql = i / 513, dist = i - ql * 513, q = q0 + ql;
    int k1 = (q - dist) & 1023;
    float wv = (float)Pf[ql * FPSTR + k1];
    if (dist != 0 && dist != 512) wv += (float)Pf[ql * FPSTR + ((q + dist) & 1023)];
    Tb[ql * TSTR + dist] = (f16)wv;
  }
  __syncthreads();
  #pragma unroll 1
  for (int cc = 0; cc < 8; ++cc) {
    stage64(Rvg + (size_t)(cc * 64) * HD, HD, Sb, FVSTR);
    __syncthreads();
    #pragma unroll
    for (int kd = 0; kd < 2; ++kd) {
      f16x8 bv;
      #pragma unroll
      for (int j = 0; j < 8; ++j) bv[j] = Sb[(kd * 32 + quad * 8 + j) * FVSTR + d];
      f16x8 aw = *(const f16x8*)(Tb + l16 * TSTR + cc * 64 + kd * 32 + quad * 8);
      co = __builtin_amdgcn_mfma_f32_16x16x32_f16(aw, bv, co, 0, 0, 0);
    }
    __syncthreads();
  }
  const float rv512 = Rvg[512 * HD + d];
  #pragma unroll
  for (int r = 0; r < 4; ++r) {
    int ql = quad * 4 + r;
    float l = lsw[0][ql] + lsw[1][ql] + lsw[2][ql] + lsw[3][ql];
    float o = co[r] + (float)Tb[ql * TSTR + 512] * rv512;
    Out[(size_t)(b * SS + q0 + ql) * DD + h * HD + d] = o / l;
  }
}

extern "C" void kernel_launch(void* const* d_in, const int* in_sizes, int n_in,
                              void* d_out, int out_size, void* d_ws, size_t ws_size,
                              hipStream_t stream) {
  const float* q  = (const float*)d_in[0];
  const float* k  = (const float*)d_in[1];
  const float* v  = (const float*)d_in[2];
  const float* rk = (const float*)d_in[3];
  const float* rv = (const float*)d_in[4];
  float* out = (float*)d_out;
  const int nblocks = BB * HH * (SS / QPB);  // 8192
  f16* vt  = (f16*)d_ws;
  f16* rvf = vt + VT_ELEMS;
  f16* rkf = rvf + RVF_ELEMS;
  f16* kt  = rkf + RKF_ELEMS;
  if (ws_size >= WS_FULL) {
    prep_kernel<<<dim3(2060 + 2048), dim3(256), 0, stream>>>(v, rv, k, rk, vt, rvf, rkf, kt);
    circ_attn_v8<true><<<dim3(nblocks), dim3(512), 0, stream>>>(
        q, k, kt, rkf, vt, rvf, out);
  } else if (ws_size >= WS_PART) {
    prep_kernel<<<dim3(2060), dim3(256), 0, stream>>>(v, rv, k, rk, vt, rvf, rkf, kt);
    circ_attn_v8<false><<<dim3(nblocks), dim3(512), 0, stream>>>(
        q, k, kt, rkf, vt, rvf, out);
  } else {
    circ_attn_mfma<<<dim3(nblocks), dim3(256), 0, stream>>>(q, k, v, rk, rv, out);
  }
}

// Round 5
// 510.320 us; speedup vs baseline: 1.1948x; 1.1948x over previous
//
#include <hip/hip_runtime.h>

typedef _Float16 f16;
typedef __attribute__((ext_vector_type(4))) _Float16 f16x4;
typedef __attribute__((ext_vector_type(8))) _Float16 f16x8;
typedef __attribute__((ext_vector_type(4))) float f32x4;
typedef __attribute__((ext_vector_type(2))) unsigned int u32x2;
typedef __attribute__((ext_vector_type(4))) unsigned int u32x4;

#define BB 8
#define SS 1024
#define DD 1024
#define HH 16
#define HD 64
#define QPB 16
#define PROW 1032   // Pf/Tf row stride (f16): 516 dw === 4 mod 32 -> conflict-free rows
#define TSTR 520    // fallback kernel strides
#define KSTR 72
#define RVSTR 520   // Rvt (folded transpose) global row stride (f16)

#define VT_ELEMS  ((size_t)BB * HH * HD * SS)   // 8,388,608
#define RVT_ELEMS ((size_t)HD * RVSTR)          // 33,280
#define RKF_ELEMS ((size_t)SS * HD)             // 65,536
#define KT_ELEMS  ((size_t)BB * HH * SS * HD)   // 8,388,608
#define WS_PART ((VT_ELEMS + RVT_ELEMS + RKF_ELEMS) * 2)
#define WS_FULL ((VT_ELEMS + RVT_ELEMS + RKF_ELEMS + KT_ELEMS) * 2)

__device__ inline f16x8 cvt16(float4 a, float4 b) {
  f16x8 h;
  h[0] = (f16)a.x; h[1] = (f16)a.y; h[2] = (f16)a.z; h[3] = (f16)a.w;
  h[4] = (f16)b.x; h[5] = (f16)b.y; h[6] = (f16)b.z; h[7] = (f16)b.w;
  return h;
}

// funnel-extract 8 f16 starting at element s (0..7) of a 16-f16 window {lo, hi}
// sh = s>>1, lob = (s&1)*16  (per-lane sh/lob OK: cndmask + alignbit)
__device__ inline f16x8 funnel8(u32x4 lo, u32x4 hi, int sh, unsigned lob) {
  unsigned e0 = (sh & 1) ? lo.y : lo.x;
  unsigned e1 = (sh & 1) ? lo.z : lo.y;
  unsigned e2 = (sh & 1) ? lo.w : lo.z;
  unsigned e3 = (sh & 1) ? hi.x : lo.w;
  unsigned e4 = (sh & 1) ? hi.y : hi.x;
  unsigned f0 = (sh & 2) ? e2 : e0;
  unsigned f1 = (sh & 2) ? e3 : e1;
  unsigned f2 = (sh & 2) ? e4 : e2;
  unsigned f3 = (sh & 2) ? ((sh & 1) ? hi.z : hi.y) : e3;
  unsigned f4 = (sh & 2) ? ((sh & 1) ? hi.w : hi.z) : e4;
  union { u32x4 u; f16x8 h; } o;
  o.u.x = __builtin_amdgcn_alignbit(f1, f0, lob);
  o.u.y = __builtin_amdgcn_alignbit(f2, f1, lob);
  o.u.z = __builtin_amdgcn_alignbit(f3, f2, lob);
  o.u.w = __builtin_amdgcn_alignbit(f4, f3, lob);
  return o.h;
}

// reverse 8 f16 in-register
__device__ inline f16x8 rev8(f16x8 v) {
  union { u32x4 u; f16x8 h; } i, o;
  i.h = v;
  o.u.x = __builtin_amdgcn_alignbit(i.u.w, i.u.w, 16);
  o.u.y = __builtin_amdgcn_alignbit(i.u.z, i.u.z, 16);
  o.u.z = __builtin_amdgcn_alignbit(i.u.y, i.u.y, 16);
  o.u.w = __builtin_amdgcn_alignbit(i.u.x, i.u.x, 16);
  return o.h;
}

// ---- prep: Vt[b][h][d][s], Rvt[d][dist] (folded transpose, dists 0..511),
//      Rkful[j][d] (palindromic cast, j=0..1023), Kt[b][h][s][d] f16 cast ----
__global__ __launch_bounds__(256, 2)
void prep_kernel(const float* __restrict__ Vg, const float* __restrict__ Rvg,
                 const float* __restrict__ Kg, const float* __restrict__ Rkg,
                 f16* __restrict__ Vt, f16* __restrict__ Rvt,
                 f16* __restrict__ Rkf, f16* __restrict__ Kt) {
  __shared__ __align__(16) f16 Tt[64 * KSTR];
  const int tid = threadIdx.x;
  const int bid = blockIdx.x;

  if (bid < 2056) {  // transpose sections (V, Rv)
    const int sr = tid >> 2, cs = (tid & 3) * 16;
    const float* src;
    int srcstride;
    f16* dst;
    int dststride, dstcol;
    if (bid < 2048) {
      int b = bid >> 8, h = (bid >> 4) & 15, tc = bid & 15;
      src = Vg + ((size_t)(b * SS + tc * 64)) * DD + h * HD;
      srcstride = DD;
      dst = Vt + ((size_t)((b * HH + h) * HD)) * SS;
      dststride = SS; dstcol = tc * 64;
    } else {
      int cc = bid - 2048;                       // 0..7, dists 0..511
      src = Rvg + ((size_t)(cc * 64)) * HD;
      srcstride = HD;
      dst = Rvt;
      dststride = RVSTR; dstcol = cc * 64;
    }
    {
      const float* s = src + (size_t)sr * srcstride + cs;
      float4 v0 = *(const float4*)(s);
      float4 v1 = *(const float4*)(s + 4);
      float4 v2 = *(const float4*)(s + 8);
      float4 v3 = *(const float4*)(s + 12);
      *(f16x8*)(Tt + sr * KSTR + cs) = cvt16(v0, v1);
      *(f16x8*)(Tt + sr * KSTR + cs + 8) = cvt16(v2, v3);
    }
    __syncthreads();
    {
      f16x8 o0, o1;
      #pragma unroll
      for (int i = 0; i < 8; ++i) o0[i] = Tt[(cs + i) * KSTR + sr];
      #pragma unroll
      for (int i = 0; i < 8; ++i) o1[i] = Tt[(cs + 8 + i) * KSTR + sr];
      f16* o = dst + (size_t)sr * dststride + dstcol + cs;
      *(f16x8*)(o) = o0;
      *(f16x8*)(o + 8) = o1;
    }
  } else if (bid < 2060) {  // Rkful: rows j = 0..1023 from Rkg[min(j,1024-j)]
    const int jrow = (bid - 2056) * 256 + tid;
    const int srcr = (jrow <= 512) ? jrow : (1024 - jrow);
    const float* s = Rkg + (size_t)srcr * HD;
    f16* o = Rkf + (size_t)jrow * HD;
    #pragma unroll
    for (int c8 = 0; c8 < 8; ++c8) {
      float4 a = *(const float4*)(s + c8 * 8);
      float4 b2 = *(const float4*)(s + c8 * 8 + 4);
      *(f16x8*)(o + c8 * 8) = cvt16(a, b2);
    }
  } else {
    // K cast -> Kt[b][h][s][d]
    const int n = bid - 2060;
    #pragma unroll
    for (int jj = 0; jj < 4; ++jj) {
      int o4 = n * 1024 + jj * 256 + tid;
      int d4 = o4 & 15;
      int s  = (o4 >> 4) & 1023;
      int bh = o4 >> 14;                 // 0..127
      int b = bh >> 4, h = bh & 15;
      float4 v = *(const float4*)(Kg + ((size_t)(b * SS + s)) * DD + h * HD + d4 * 4);
      f16x4 hv; hv[0] = (f16)v.x; hv[1] = (f16)v.y; hv[2] = (f16)v.z; hv[3] = (f16)v.w;
      *(f16x4*)(Kt + (size_t)o4 * 4) = hv;
    }
  }
}

// ---- main v9: LDS-pipe reduction. v7 structure + v8b's vectorized Phase T
// (b64 T-writes, full-width Tf over Rkful) + v8b's b64+alignbit bias reads +
// stride 1032 (bank = 4*((l16+quad)%8): conflict-free rows) + lane-remapped
// Phase W (quad lanes spread over 16 rows). W table overwrites dead Tf;
// partials stage in dead Pf. LDS 66.6 KB -> 2 blocks/CU.
template <bool KT16>
__global__ __launch_bounds__(512, 4)
void circ_attn_v9(const float* __restrict__ Qg, const float* __restrict__ Kg,
                  const f16* __restrict__ Kt, const f16* __restrict__ Rkf,
                  const float* __restrict__ Rvg,
                  const f16* __restrict__ Vt, const f16* __restrict__ Rvt,
                  float* __restrict__ Out) {
  __shared__ __align__(16) f16 Pf[QPB * PROW];
  __shared__ __align__(16) f16 Tf[QPB * PROW];   // T table, later reused as W table
  __shared__ float lsw[8][16];
  __shared__ float w512[16];

  // XCD swizzle: all 64 q-blocks of one (b,h) land on XCD (g & 7)
  const int i = blockIdx.x;
  const int g = ((i >> 9) << 3) | (i & 7);   // (b,h) group 0..127
  const int m = (i >> 3) & 63;               // q-block 0..63
  const int b = g >> 4;
  const int h = g & 15;
  const int q0 = m * QPB;

  const int tid = threadIdx.x;
  const int w = tid >> 6;        // 0..7
  const int lane = tid & 63;
  const int quad = lane >> 4;
  const int l16 = lane & 15;
  const int wd = w & 3;          // output d-group 0..3
  const int wh = w >> 2;         // k-half / dist-half 0..1

  // ---- Q fragments straight from global (A-layout == B-layout) ----
  f16x8 qf0, qf1;
  {
    const float* qrow = Qg + ((size_t)(b * SS + q0 + l16)) * DD + h * HD;
    float4 a0 = *(const float4*)(qrow + quad * 8);
    float4 a1 = *(const float4*)(qrow + quad * 8 + 4);
    float4 a2 = *(const float4*)(qrow + 32 + quad * 8);
    float4 a3 = *(const float4*)(qrow + 32 + quad * 8 + 4);
    qf0 = cvt16(a0, a1);
    qf1 = cvt16(a2, a3);
  }

  // ---- Phase T: Tf[q][j] = Q . Rkful^T; swapped operands -> lane holds
  //      (q=l16, j=cc*128+w*16+quad*4+r) -> vectorized b64 writes ----
  {
    const f16* rkp = Rkf + ((size_t)(w * 16 + l16)) * HD + quad * 8;
    f16x8 t0 = *(const f16x8*)(rkp);
    f16x8 t1 = *(const f16x8*)(rkp + 32);
    #pragma unroll
    for (int cc = 0; cc < 8; ++cc) {
      f16x8 c0 = t0, c1 = t1;
      if (cc < 7) {
        const f16* np = rkp + (size_t)(cc + 1) * 128 * HD;
        t0 = *(const f16x8*)(np);
        t1 = *(const f16x8*)(np + 32);
      }
      f32x4 c = {0.f, 0.f, 0.f, 0.f};
      c = __builtin_amdgcn_mfma_f32_16x16x32_f16(c0, qf0, c, 0, 0, 0);
      c = __builtin_amdgcn_mfma_f32_16x16x32_f16(c1, qf1, c, 0, 0, 0);
      f16x4 tw;
      #pragma unroll
      for (int r = 0; r < 4; ++r) tw[r] = (f16)c[r];
      *(f16x4*)(Tf + l16 * PROW + cc * 128 + w * 16 + quad * 4) = tw;
    }
  }
  // pad Tf cols 1024..1031: copy cols 0..7 (written by wave 0 at cc=0)
  if (w == 0 && lane < 16)
    *(f16x8*)(Tf + lane * PROW + 1024) = *(const f16x8*)(Tf + lane * PROW);

  // Phase A initial K prefetch (independent of Tf, issued before barrier 1)
  const f16* kp16 = KT16 ?
      (Kt + (((size_t)(b * HH + h) << 10) + w * 16 + l16) * HD + quad * 8) : nullptr;
  const float* kp32 = KT16 ? nullptr :
      (Kg + ((size_t)(b * SS + w * 16 + l16)) * DD + h * HD + quad * 8);
  f16x8 ka0, ka1, kb0, kb1;
  float4 f0, f1, f2, f3;
  if (KT16) {
    ka0 = *(const f16x8*)(kp16);
    ka1 = *(const f16x8*)(kp16 + 32);
    kb0 = *(const f16x8*)(kp16 + 128 * HD);
    kb1 = *(const f16x8*)(kp16 + 128 * HD + 32);
  } else {
    f0 = *(const float4*)(kp32);
    f1 = *(const float4*)(kp32 + 4);
    f2 = *(const float4*)(kp32 + 32);
    f3 = *(const float4*)(kp32 + 36);
  }
  __syncthreads();   // barrier 1: Tf ready

  // ---- Phase A: S^T = K . Q^T ; bias via aligned b64-pair + alignbit from Tf ----
  {
    float psum = 0.f;
    #pragma unroll
    for (int kc = 0; kc < 8; ++kc) {
      f16x8 c0, c1;
      if (KT16) {
        c0 = ka0; c1 = ka1; ka0 = kb0; ka1 = kb1;
        if (kc < 6) {
          const f16* np = kp16 + (size_t)(kc + 2) * 128 * HD;
          kb0 = *(const f16x8*)(np);
          kb1 = *(const f16x8*)(np + 32);
        }
      } else {
        c0 = cvt16(f0, f1); c1 = cvt16(f2, f3);
        if (kc < 7) {
          const float* s = kp32 + (size_t)(kc + 1) * 128 * DD;
          f0 = *(const float4*)(s);      f1 = *(const float4*)(s + 4);
          f2 = *(const float4*)(s + 32); f3 = *(const float4*)(s + 36);
        }
      }
      const int kb_ = kc * 128 + w * 16 + quad * 4;
      const int qg = q0 + l16;
      const int j0 = (qg - kb_) & 1023;          // bias col for r=0
      const int jm = (j0 - 3) & 1023;            // window start (r=3)
      const int a0 = jm & ~3;
      const f16* tp = Tf + l16 * PROW + a0;
      u32x2 lo = *(const u32x2*)(tp);
      u32x2 hi = *(const u32x2*)(tp + 4);
      const int s4 = jm & 3;
      unsigned D0 = lo.x, D1 = lo.y, D2 = hi.x, D3 = hi.y;
      unsigned A0 = (s4 & 2) ? D1 : D0;
      unsigned A1 = (s4 & 2) ? D2 : D1;
      unsigned A2 = (s4 & 2) ? D3 : D2;
      unsigned lob = (unsigned)((s4 & 1) * 16);
      union { u32x2 u; f16x4 hh; } tw;
      tw.u.x = __builtin_amdgcn_alignbit(A1, A0, lob);
      tw.u.y = __builtin_amdgcn_alignbit(A2, A1, lob);
      // tw.hh[t] = Tf[q][jm + t]; r-th value at j = j0 - r = jm + 3 - r
      f32x4 c = {0.f, 0.f, 0.f, 0.f};
      c = __builtin_amdgcn_mfma_f32_16x16x32_f16(c0, qf0, c, 0, 0, 0);
      c = __builtin_amdgcn_mfma_f32_16x16x32_f16(c1, qf1, c, 0, 0, 0);
      f16x4 pv;
      #pragma unroll
      for (int r = 0; r < 4; ++r) {
        float sc = fmaf(c[r], 0.125f, (float)tw.hh[3 - r]);
        float p = __expf(sc);           // no max-subtract: |sc| small, fp32-safe
        pv[r] = (f16)p;
        psum += p;
      }
      *(f16x4*)(Pf + l16 * PROW + kb_) = pv;
    }
    psum += __shfl_xor(psum, 16);
    psum += __shfl_xor(psum, 32);
    if (quad == 0) lsw[w][l16] = psum;
  }
  // circular pad: Pf[q][1024..1031] = Pf[q][0..7] (wave 0 wrote cols 0..7 at kc=0)
  if (w == 0 && lane < 16)
    *(f16x8*)(Pf + lane * PROW + 1024) = *(const f16x8*)(Pf + lane * PROW);

  // Phase B initial V prefetch (independent of Pf); wave w: d-group wd, k-half wh
  const f16* vtp = Vt + ((size_t)((b * HH + h) * HD) + wd * 16 + l16) * SS
                      + wh * 512 + quad * 8;
  f16x8 va0 = *(const f16x8*)(vtp);
  f16x8 va1 = *(const f16x8*)(vtp + 32);
  f16x8 vb0 = *(const f16x8*)(vtp + 64);
  f16x8 vb1 = *(const f16x8*)(vtp + 96);
  __syncthreads();   // barrier 2: Pf + pad + lsw ready; Tf now dead

  // ---- Phase B: co_partial = P[., k-half] . V[k-half, d-group]  (8 iters) ----
  f32x4 co = {0.f, 0.f, 0.f, 0.f};
  {
    #pragma unroll
    for (int kc = 0; kc < 8; ++kc) {
      f16x8 cb0 = va0, cb1 = va1;
      va0 = vb0; va1 = vb1;
      if (kc < 6) {
        vb0 = *(const f16x8*)(vtp + (kc + 2) * 64);
        vb1 = *(const f16x8*)(vtp + (kc + 2) * 64 + 32);
      }
      f16x8 ap0 = *(const f16x8*)(Pf + l16 * PROW + wh * 512 + kc * 64 + quad * 8);
      f16x8 ap1 = *(const f16x8*)(Pf + l16 * PROW + wh * 512 + kc * 64 + 32 + quad * 8);
      co = __builtin_amdgcn_mfma_f32_16x16x32_f16(ap0, cb0, co, 0, 0, 0);
      co = __builtin_amdgcn_mfma_f32_16x16x32_f16(ap1, cb1, co, 0, 0, 0);
    }
  }

  // Wrelv Rv prefetch: all 4 iterations issued here, hidden under Phase W compute
  const f16* rvp = Rvt + ((size_t)(wd * 16 + l16)) * RVSTR + wh * 256 + quad * 8;
  f16x8 r0[4], r1[4];
  #pragma unroll
  for (int t = 0; t < 4; ++t) {
    r0[t] = *(const f16x8*)(rvp + t * 64);
    r1[t] = *(const f16x8*)(rvp + t * 64 + 32);
  }

  // ---- Phase W: fold P -> W[ql][dist] into Tf (dead since barrier 2).
  // Lane map: ql = l16 (16 rows across a quad's lanes -> conflict-free),
  // gg = it*32 + w*4 + quad (dist group: dists gg*8 .. gg*8+7) ----
  #pragma unroll
  for (int it = 0; it < 2; ++it) {
    const int ql = l16;
    const int gg = it * 32 + w * 4 + quad;
    const int qq = q0 + ql;
    const f16* rowp = Pf + ql * PROW;
    // plus side: window at bp = (qq + 8*gg) & 1023; bp mod 8 == qq mod 8 -> bp >= sp
    const int sp = qq & 7;
    const int bp = (qq + 8 * gg) & 1023;
    const f16* app = rowp + (bp - sp);
    u32x4 pA = *(const u32x4*)(app);
    u32x4 pB = *(const u32x4*)(app + 8);
    // minus side: ascending window at bm = (qq - 8*gg - 7) & 1023; bm mod 8 == sm
    const int sm = (qq + 1) & 7;
    const int bm = (qq - 8 * gg - 7) & 1023;
    const f16* apm = rowp + (bm - sm);
    u32x4 mA = *(const u32x4*)(apm);
    u32x4 mB = *(const u32x4*)(apm + 8);
    f16x8 pp = funnel8(pA, pB, sp >> 1, (unsigned)((sp & 1) * 16));
    f16x8 mw = funnel8(mA, mB, sm >> 1, (unsigned)((sm & 1) * 16));
    f16x8 rm = rev8(mw);               // rm[t] = P[(qq - 8*gg - t) & 1023]
    f16x8 wv = rm + pp;
    if (gg == 0) wv[0] = rm[0];        // dist 0: single term P[q]
    *(f16x8*)(Tf + ql * PROW + gg * 8) = wv;
  }
  if (tid < 16)                        // dist 512: single term P[(q+512) mod S]
    w512[tid] = (float)Pf[tid * PROW + ((q0 + tid + 512) & 1023)];
  __syncthreads();   // barrier 3: W table ready; all Pf reads complete

  // ---- Phase Wrelv: co_partial += W[., dist-half] . Rvt[dist-half, d-group] ----
  {
    #pragma unroll
    for (int cc = 0; cc < 4; ++cc) {
      f16x8 aw0 = *(const f16x8*)(Tf + l16 * PROW + wh * 256 + cc * 64 + quad * 8);
      f16x8 aw1 = *(const f16x8*)(Tf + l16 * PROW + wh * 256 + cc * 64 + 32 + quad * 8);
      co = __builtin_amdgcn_mfma_f32_16x16x32_f16(aw0, r0[cc], co, 0, 0, 0);
      co = __builtin_amdgcn_mfma_f32_16x16x32_f16(aw1, r1[cc], co, 0, 0, 0);
    }
  }

  // ---- pairwise partial-sum reduction through Pf (dead since barrier 3) ----
  if (w >= 4)
    *(f32x4*)((float*)Pf + ((size_t)(wd * 64 + lane)) * 4) = co;
  __syncthreads();   // barrier 4: partials staged
  if (w < 4) {
    f32x4 part = *(const f32x4*)((const float*)Pf + ((size_t)(w * 64 + lane)) * 4);
    co += part;
    // ---- finalize: dist-512 rel_v term + normalize + store ----
    const int d = w * 16 + l16;
    const float rv512 = Rvg[512 * HD + d];
    #pragma unroll
    for (int r = 0; r < 4; ++r) {
      int ql = quad * 4 + r;
      float l = 0.f;
      #pragma unroll
      for (int j = 0; j < 8; ++j) l += lsw[j][ql];
      float o = co[r] + w512[ql] * rv512;
      Out[((size_t)(b * SS + q0 + ql)) * DD + h * HD + d] = o / l;
    }
  }
}

// ---- fallback (R2-style, used only if ws_size is tiny) ----
#define FPSTR 1032
#define FVSTR 68
__global__ __launch_bounds__(256, 2)
void circ_attn_mfma(const float* __restrict__ Qg, const float* __restrict__ Kg,
                    const float* __restrict__ Vg, const float* __restrict__ Rkg,
                    const float* __restrict__ Rvg, float* __restrict__ Out) {
  __shared__ __align__(16) f16 Pf[QPB * FPSTR];
  __shared__ __align__(16) f16 Tb[QPB * TSTR];
  __shared__ __align__(16) f16 Sb[64 * KSTR];
  __shared__ __align__(16) f16 Qb[QPB * KSTR];
  __shared__ float lsw[4][16];
  const int bid = blockIdx.x;
  const int b = bid >> 10, h = (bid >> 6) & 15, q0 = (bid & 63) * QPB;
  const int tid = threadIdx.x, w = tid >> 6, lane = tid & 63;
  const int quad = lane >> 4, l16 = lane & 15;
  auto stage64 = [&](const float* src, int rstride, f16* dst, int dstr) {
    #pragma unroll
    for (int jj = 0; jj < 4; ++jj) {
      int i = jj * 256 + tid;
      int r = i >> 4, c = (i & 15) << 2;
      float4 v = *(const float4*)(src + (size_t)r * rstride + c);
      f16x4 hv; hv[0] = (f16)v.x; hv[1] = (f16)v.y; hv[2] = (f16)v.z; hv[3] = (f16)v.w;
      *(f16x4*)(dst + r * dstr + c) = hv;
    }
  };
  {
    int r = tid >> 4, c = (tid & 15) << 2;
    float4 v = *(const float4*)(Qg + (size_t)(b * SS + q0 + r) * DD + h * HD + c);
    f16x4 hv; hv[0] = (f16)v.x; hv[1] = (f16)v.y; hv[2] = (f16)v.z; hv[3] = (f16)v.w;
    *(f16x4*)(Qb + r * KSTR + c) = hv;
  }
  __syncthreads();
  const f16x8 qf0 = *(const f16x8*)(Qb + l16 * KSTR + quad * 8);
  const f16x8 qf1 = *(const f16x8*)(Qb + l16 * KSTR + 32 + quad * 8);
  #pragma unroll 1
  for (int cc = 0; cc < 8; ++cc) {
    stage64(Rkg + (size_t)(cc * 64) * HD, HD, Sb, KSTR);
    __syncthreads();
    f16x8 rk0 = *(const f16x8*)(Sb + (w * 16 + l16) * KSTR + quad * 8);
    f16x8 rk1 = *(const f16x8*)(Sb + (w * 16 + l16) * KSTR + 32 + quad * 8);
    f32x4 c = {0.f, 0.f, 0.f, 0.f};
    c = __builtin_amdgcn_mfma_f32_16x16x32_f16(qf0, rk0, c, 0, 0, 0);
    c = __builtin_amdgcn_mfma_f32_16x16x32_f16(qf1, rk1, c, 0, 0, 0);
    const int dbase = cc * 64 + w * 16 + l16;
    #pragma unroll
    for (int r = 0; r < 4; ++r) Tb[(quad * 4 + r) * TSTR + dbase] = (f16)c[r];
    __syncthreads();
  }
  if (w == 0) {
    float t = 0.f;
    #pragma unroll
    for (int i = 0; i < 16; ++i)
      t += (float)Qb[l16 * KSTR + quad * 16 + i] * Rkg[512 * HD + quad * 16 + i];
    t += __shfl_xor(t, 16); t += __shfl_xor(t, 32);
    if (quad == 0) Tb[l16 * TSTR + 512] = (f16)t;
  }
  float psum = 0.f;
  #pragma unroll 1
  for (int kc = 0; kc < 16; ++kc) {
    stage64(Kg + (size_t)(b * SS + kc * 64) * DD + h * HD, DD, Sb, KSTR);
    __syncthreads();
    f16x8 ka0 = *(const f16x8*)(Sb + (w * 16 + l16) * KSTR + quad * 8);
    f16x8 ka1 = *(const f16x8*)(Sb + (w * 16 + l16) * KSTR + 32 + quad * 8);
    f32x4 c = {0.f, 0.f, 0.f, 0.f};
    c = __builtin_amdgcn_mfma_f32_16x16x32_f16(ka0, qf0, c, 0, 0, 0);
    c = __builtin_amdgcn_mfma_f32_16x16x32_f16(ka1, qf1, c, 0, 0, 0);
    const int kb = kc * 64 + w * 16 + quad * 4;
    const int q = q0 + l16;
    f16x4 pv;
    #pragma unroll
    for (int r = 0; r < 4; ++r) {
      int key = kb + r;
      int j = (q - key) & 1023;
      int dist = (j < 1024 - j) ? j : 1024 - j;
      float s = c[r] * 0.125f + (float)Tb[l16 * TSTR + dist];
      float p = __expf(s);
      pv[r] = (f16)p;
      psum += p;
    }
    *(f16x4*)(Pf + l16 * FPSTR + kb) = pv;
    __syncthreads();
  }
  psum += __shfl_xor(psum, 16); psum += __shfl_xor(psum, 32);
  if (quad == 0) lsw[w][l16] = psum;
  f32x4 co = {0.f, 0.f, 0.f, 0.f};
  const int d = w * 16 + l16;
  #pragma unroll 1
  for (int kc = 0; kc < 16; ++kc) {
    stage64(Vg + (size_t)(b * SS + kc * 64) * DD + h * HD, DD, Sb, FVSTR);
    __syncthreads();
    #pragma unroll
    for (int kd = 0; kd < 2; ++kd) {
      f16x8 bv;
      #pragma unroll
      for (int j = 0; j < 8; ++j) bv[j] = Sb[(kd * 32 + quad * 8 + j) * FVSTR + d];
      f16x8 ap = *(const f16x8*)(Pf + l16 * FPSTR + kc * 64 + kd * 32 + quad * 8);
      co = __builtin_amdgcn_mfma_f32_16x16x32_f16(ap, bv, co, 0, 0, 0);
    }
    __syncthreads();
  }
  #pragma unroll 1
  for (int i = tid; i < QPB * 513; i += 256) {
    int ql = i / 513, dist = i - ql * 513, q = q0 + ql;
    int k1 = (q - dist) & 1023;
    float wv = (float)Pf[ql * FPSTR + k1];
    if (dist != 0 && dist != 512) wv += (float)Pf[ql * FPSTR + ((q + dist) & 1023)];
    Tb[ql * TSTR + dist] = (f16)wv;
  }
  __syncthreads();
  #pragma unroll 1
  for (int cc = 0; cc < 8; ++cc) {
    stage64(Rvg + (size_t)(cc * 64) * HD, HD, Sb, FVSTR);
    __syncthreads();
    #pragma unroll
    for (int kd = 0; kd < 2; ++kd) {
      f16x8 bv;
      #pragma unroll
      for (int j = 0; j < 8; ++j) bv[j] = Sb[(kd * 32 + quad * 8 + j) * FVSTR + d];
      f16x8 aw = *(const f16x8*)(Tb + l16 * TSTR + cc * 64 + kd * 32 + quad * 8);
      co = __builtin_amdgcn_mfma_f32_16x16x32_f16(aw, bv, co, 0, 0, 0);
    }
    __syncthreads();
  }
  const float rv512 = Rvg[512 * HD + d];
  #pragma unroll
  for (int r = 0; r < 4; ++r) {
    int ql = quad * 4 + r;
    float l = lsw[0][ql] + lsw[1][ql] + lsw[2][ql] + lsw[3][ql];
    float o = co[r] + (float)Tb[ql * TSTR + 512] * rv512;
    Out[(size_t)(b * SS + q0 + ql) * DD + h * HD + d] = o / l;
  }
}

extern "C" void kernel_launch(void* const* d_in, const int* in_sizes, int n_in,
                              void* d_out, int out_size, void* d_ws, size_t ws_size,
                              hipStream_t stream) {
  const float* q  = (const float*)d_in[0];
  const float* k  = (const float*)d_in[1];
  const float* v  = (const float*)d_in[2];
  const float* rk = (const float*)d_in[3];
  const float* rv = (const float*)d_in[4];
  float* out = (float*)d_out;
  const int nblocks = BB * HH * (SS / QPB);  // 8192
  f16* vt  = (f16*)d_ws;
  f16* rvt = vt + VT_ELEMS;
  f16* rkf = rvt + RVT_ELEMS;
  f16* kt  = rkf + RKF_ELEMS;
  if (ws_size >= WS_FULL) {
    prep_kernel<<<dim3(2060 + 2048), dim3(256), 0, stream>>>(v, rv, k, rk, vt, rvt, rkf, kt);
    circ_attn_v9<true><<<dim3(nblocks), dim3(512), 0, stream>>>(
        q, k, kt, rkf, rv, vt, rvt, out);
  } else if (ws_size >= WS_PART) {
    prep_kernel<<<dim3(2060), dim3(256), 0, stream>>>(v, rv, k, rk, vt, rvt, rkf, kt);
    circ_attn_v9<false><<<dim3(nblocks), dim3(512), 0, stream>>>(
        q, k, kt, rkf, rv, vt, rvt, out);
  } else {
    circ_attn_mfma<<<dim3(nblocks), dim3(256), 0, stream>>>(q, k, v, rk, rv, out);
  }
}

// Round 6
// 387.989 us; speedup vs baseline: 1.5716x; 1.3153x over previous
//
#include <hip/hip_runtime.h>

typedef _Float16 f16;
typedef __attribute__((ext_vector_type(4))) _Float16 f16x4;
typedef __attribute__((ext_vector_type(8))) _Float16 f16x8;
typedef __attribute__((ext_vector_type(4))) float f32x4;
typedef __attribute__((ext_vector_type(4))) unsigned int u32x4;

#define BB 8
#define SS 1024
#define DD 1024
#define HH 16
#define HD 64
#define QPB 32      // q-rows per block (2 subtiles of 16) -- halves stream traffic
#define PROW 1040   // Pf row len (f16): cols 0..1023 + 8 circular pad, 16B-aligned
#define TSTR 520    // T/W table row stride (f16)
#define KSTR 72     // prep-kernel LDS staging stride
#define RVSTR 520   // Rvt global row stride (f16)

#define VT_ELEMS  ((size_t)BB * HH * HD * SS)   // 8,388,608
#define RVT_ELEMS ((size_t)HD * RVSTR)          // 33,280
#define RKT_ELEMS ((size_t)513 * HD)            // 32,832
#define KT_ELEMS  ((size_t)BB * HH * SS * HD)   // 8,388,608
#define WS_PART ((VT_ELEMS + RVT_ELEMS + RKT_ELEMS) * 2)
#define WS_FULL ((VT_ELEMS + RVT_ELEMS + RKT_ELEMS + KT_ELEMS) * 2)

__device__ inline f16x8 cvt16(float4 a, float4 b) {
  f16x8 h;
  h[0] = (f16)a.x; h[1] = (f16)a.y; h[2] = (f16)a.z; h[3] = (f16)a.w;
  h[4] = (f16)b.x; h[5] = (f16)b.y; h[6] = (f16)b.z; h[7] = (f16)b.w;
  return h;
}

// funnel-extract 8 f16 starting at element s (0..7) of a 16-f16 window {lo, hi}
__device__ inline f16x8 funnel8(u32x4 lo, u32x4 hi, int sh, unsigned lob) {
  unsigned e0 = (sh & 1) ? lo.y : lo.x;
  unsigned e1 = (sh & 1) ? lo.z : lo.y;
  unsigned e2 = (sh & 1) ? lo.w : lo.z;
  unsigned e3 = (sh & 1) ? hi.x : lo.w;
  unsigned e4 = (sh & 1) ? hi.y : hi.x;
  unsigned f0 = (sh & 2) ? e2 : e0;
  unsigned f1 = (sh & 2) ? e3 : e1;
  unsigned f2 = (sh & 2) ? e4 : e2;
  unsigned f3 = (sh & 2) ? ((sh & 1) ? hi.z : hi.y) : e3;
  unsigned f4 = (sh & 2) ? ((sh & 1) ? hi.w : hi.z) : e4;
  union { u32x4 u; f16x8 h; } o;
  o.u.x = __builtin_amdgcn_alignbit(f1, f0, lob);
  o.u.y = __builtin_amdgcn_alignbit(f2, f1, lob);
  o.u.z = __builtin_amdgcn_alignbit(f3, f2, lob);
  o.u.w = __builtin_amdgcn_alignbit(f4, f3, lob);
  return o.h;
}

// reverse 8 f16 in-register
__device__ inline f16x8 rev8(f16x8 v) {
  union { u32x4 u; f16x8 h; } i, o;
  i.h = v;
  o.u.x = __builtin_amdgcn_alignbit(i.u.w, i.u.w, 16);
  o.u.y = __builtin_amdgcn_alignbit(i.u.z, i.u.z, 16);
  o.u.z = __builtin_amdgcn_alignbit(i.u.y, i.u.y, 16);
  o.u.w = __builtin_amdgcn_alignbit(i.u.x, i.u.x, 16);
  return o.h;
}

// ---- prep: Vt[b][h][d][s], Rvt[d][dist] (transposes), Kt[b][h][s][d], Rkt f16 casts ----
__global__ __launch_bounds__(256, 2)
void prep_kernel(const float* __restrict__ Vg, const float* __restrict__ Rvg,
                 const float* __restrict__ Kg, const float* __restrict__ Rkg,
                 f16* __restrict__ Vt, f16* __restrict__ Rvt,
                 f16* __restrict__ Rkt, f16* __restrict__ Kt) {
  __shared__ __align__(16) f16 Tt[64 * KSTR];
  const int tid = threadIdx.x;
  const int bid = blockIdx.x;

  if (bid < 2056) {  // transpose sections (V, Rv)
    const int sr = tid >> 2, cs = (tid & 3) * 16;
    const float* src;
    int srcstride;
    f16* dst;
    int dststride, dstcol;
    if (bid < 2048) {
      int b = bid >> 8, h = (bid >> 4) & 15, tc = bid & 15;
      src = Vg + ((size_t)(b * SS + tc * 64)) * DD + h * HD;
      srcstride = DD;
      dst = Vt + ((size_t)((b * HH + h) * HD)) * SS;
      dststride = SS; dstcol = tc * 64;
    } else {
      int cc = bid - 2048;                       // 0..7, dists 0..511
      src = Rvg + ((size_t)(cc * 64)) * HD;
      srcstride = HD;
      dst = Rvt;
      dststride = RVSTR; dstcol = cc * 64;
    }
    {
      const float* s = src + (size_t)sr * srcstride + cs;
      float4 v0 = *(const float4*)(s);
      float4 v1 = *(const float4*)(s + 4);
      float4 v2 = *(const float4*)(s + 8);
      float4 v3 = *(const float4*)(s + 12);
      *(f16x8*)(Tt + sr * KSTR + cs) = cvt16(v0, v1);
      *(f16x8*)(Tt + sr * KSTR + cs + 8) = cvt16(v2, v3);
    }
    __syncthreads();
    {
      f16x8 o0, o1;
      #pragma unroll
      for (int i = 0; i < 8; ++i) o0[i] = Tt[(cs + i) * KSTR + sr];
      #pragma unroll
      for (int i = 0; i < 8; ++i) o1[i] = Tt[(cs + 8 + i) * KSTR + sr];
      f16* o = dst + (size_t)sr * dststride + dstcol + cs;
      *(f16x8*)(o) = o0;
      *(f16x8*)(o + 8) = o1;
    }
  } else if (bid < 2058) {  // Rk cast: 513*64 = 32832 elems, 2 blocks
    const int base = (bid - 2056) * 16416;
    for (int j = tid; j < 16416; j += 256)
      Rkt[base + j] = (f16)Rkg[base + j];
  } else {
    // K cast -> Kt[b][h][s][d]
    const int n = bid - 2058;
    #pragma unroll
    for (int jj = 0; jj < 4; ++jj) {
      int o4 = n * 1024 + jj * 256 + tid;
      int d4 = o4 & 15;
      int s  = (o4 >> 4) & 1023;
      int bh = o4 >> 14;                 // 0..127
      int b = bh >> 4, h = bh & 15;
      float4 v = *(const float4*)(Kg + ((size_t)(b * SS + s)) * DD + h * HD + d4 * 4);
      f16x4 hv; hv[0] = (f16)v.x; hv[1] = (f16)v.y; hv[2] = (f16)v.z; hv[3] = (f16)v.w;
      *(f16x4*)(Kt + (size_t)o4 * 4) = hv;
    }
  }
}

// ---- main v10: QPB=32 / 1024-thr / 16-wave blocks, v7 mechanisms unchanged.
// Every K/V/Rk/Rv fragment load feeds TWO q-subtiles (rows 0-15, 16-31) -> total
// stream requests across the kernel HALVE (the decisive request-throughput test).
// LDS 102 KB -> 1 block/CU (16 waves = 4/SIMD).
template <bool KT16>
__global__ __launch_bounds__(1024, 4)
void circ_attn_v10(const float* __restrict__ Qg, const float* __restrict__ Kg,
                   const f16* __restrict__ Kt, const f16* __restrict__ Rkt,
                   const float* __restrict__ Rkg, const float* __restrict__ Rvg,
                   const f16* __restrict__ Vt, const f16* __restrict__ Rvt,
                   float* __restrict__ Out) {
  __shared__ __align__(16) f16 Pf[QPB * PROW];    // 66,560 B
  __shared__ __align__(16) f16 Tb[QPB * TSTR];    // 33,280 B (T table, then W table)
  __shared__ float lsw[16][32];                   // 2 KB
  __shared__ float w512[32];

  // XCD swizzle: all 32 q-blocks of one (b,h) land on XCD (i & 7)
  const int i = blockIdx.x;
  const int g = ((i >> 8) << 3) | (i & 7);   // (b,h) group 0..127
  const int m = (i >> 3) & 31;               // q-block 0..31
  const int b = g >> 4;
  const int h = g & 15;
  const int q0 = m * QPB;

  const int tid = threadIdx.x;
  const int w = tid >> 6;        // 0..15
  const int lane = tid & 63;
  const int quad = lane >> 4;
  const int l16 = lane & 15;
  const int wd = w & 3;          // output d-group 0..3
  const int wh = w >> 2;         // k-quarter / dist-quarter 0..3

  // ---- Q fragments for BOTH subtiles (rows q0+l16 and q0+16+l16) ----
  f16x8 qa0, qa1, qb0, qb1;
  {
    const float* qr = Qg + ((size_t)(b * SS + q0 + l16)) * DD + h * HD;
    float4 a0 = *(const float4*)(qr + quad * 8);
    float4 a1 = *(const float4*)(qr + quad * 8 + 4);
    float4 a2 = *(const float4*)(qr + 32 + quad * 8);
    float4 a3 = *(const float4*)(qr + 32 + quad * 8 + 4);
    qa0 = cvt16(a0, a1); qa1 = cvt16(a2, a3);
    const float* qr2 = qr + 16 * DD;
    float4 b0 = *(const float4*)(qr2 + quad * 8);
    float4 b1 = *(const float4*)(qr2 + quad * 8 + 4);
    float4 b2 = *(const float4*)(qr2 + 32 + quad * 8);
    float4 b3 = *(const float4*)(qr2 + 32 + quad * 8 + 4);
    qb0 = cvt16(b0, b1); qb1 = cvt16(b2, b3);
  }

  // ---- Phase T: T[q][dist] for 32 rows; wave w covers dists cc*256 + w*16 + l16 ----
  {
    const f16* rkp = Rkt + ((size_t)(w * 16 + l16)) * HD + quad * 8;
    f16x8 t0[2], t1[2];
    #pragma unroll
    for (int t = 0; t < 2; ++t) {
      const f16* np = rkp + (size_t)t * 256 * HD;
      t0[t] = *(const f16x8*)(np);
      t1[t] = *(const f16x8*)(np + 32);
    }
    #pragma unroll
    for (int cc = 0; cc < 2; ++cc) {
      f32x4 ca = {0.f, 0.f, 0.f, 0.f};
      ca = __builtin_amdgcn_mfma_f32_16x16x32_f16(qa0, t0[cc], ca, 0, 0, 0);
      ca = __builtin_amdgcn_mfma_f32_16x16x32_f16(qa1, t1[cc], ca, 0, 0, 0);
      f32x4 cb = {0.f, 0.f, 0.f, 0.f};
      cb = __builtin_amdgcn_mfma_f32_16x16x32_f16(qb0, t0[cc], cb, 0, 0, 0);
      cb = __builtin_amdgcn_mfma_f32_16x16x32_f16(qb1, t1[cc], cb, 0, 0, 0);
      const int dbase = cc * 256 + w * 16 + l16;
      #pragma unroll
      for (int r = 0; r < 4; ++r) {
        Tb[(quad * 4 + r) * TSTR + dbase] = (f16)ca[r];
        Tb[(16 + quad * 4 + r) * TSTR + dbase] = (f16)cb[r];
      }
    }
  }
  // dist 512 (wave 0 only, f32 path) for both subtiles
  if (w == 0) {
    const float* rk = Rkg + 512 * HD;
    float ta = 0.f, tb = 0.f;
    #pragma unroll
    for (int j = 0; j < 8; ++j) {
      float rkv0 = rk[quad * 8 + j], rkv1 = rk[32 + quad * 8 + j];
      ta += (float)qa0[j] * rkv0 + (float)qa1[j] * rkv1;
      tb += (float)qb0[j] * rkv0 + (float)qb1[j] * rkv1;
    }
    ta += __shfl_xor(ta, 16); ta += __shfl_xor(ta, 32);
    tb += __shfl_xor(tb, 16); tb += __shfl_xor(tb, 32);
    if (quad == 0) {
      Tb[l16 * TSTR + 512] = (f16)ta;
      Tb[(16 + l16) * TSTR + 512] = (f16)tb;
    }
  }

  // Phase A K prefetch: all 4 iters, issued before barrier 1 (independent of Tb)
  const f16* kp16 = KT16 ?
      (Kt + (((size_t)(b * HH + h) << 10) + w * 16 + l16) * HD + quad * 8) : nullptr;
  const float* kp32 = KT16 ? nullptr :
      (Kg + ((size_t)(b * SS + w * 16 + l16)) * DD + h * HD + quad * 8);
  f16x8 k0[4], k1[4];
  float4 f0, f1, f2, f3;
  if (KT16) {
    #pragma unroll
    for (int t = 0; t < 4; ++t) {
      const f16* np = kp16 + (size_t)t * 256 * HD;
      k0[t] = *(const f16x8*)(np);
      k1[t] = *(const f16x8*)(np + 32);
    }
  } else {
    f0 = *(const float4*)(kp32);
    f1 = *(const float4*)(kp32 + 4);
    f2 = *(const float4*)(kp32 + 32);
    f3 = *(const float4*)(kp32 + 36);
  }
  __syncthreads();   // barrier 1: Tb(T) ready

  // ---- Phase A: S^T = K . Q^T for both subtiles; wave w covers k = kc*256+w*16+.. ----
  {
    float psa = 0.f, psb = 0.f;
    #pragma unroll
    for (int kc = 0; kc < 4; ++kc) {
      f16x8 c0, c1;
      if (KT16) {
        c0 = k0[kc]; c1 = k1[kc];
      } else {
        c0 = cvt16(f0, f1); c1 = cvt16(f2, f3);
        if (kc < 3) {
          const float* s = kp32 + (size_t)(kc + 1) * 256 * DD;
          f0 = *(const float4*)(s);      f1 = *(const float4*)(s + 4);
          f2 = *(const float4*)(s + 32); f3 = *(const float4*)(s + 36);
        }
      }
      const int kb_ = kc * 256 + w * 16 + quad * 4;
      // bias gathers for both subtiles (independent of MFMA result)
      const int j0a = ((q0 + l16) - kb_) & 1023;
      const int j0b = (j0a + 16) & 1023;
      float tva[4], tvb[4];
      #pragma unroll
      for (int r = 0; r < 4; ++r) {
        int jra = (j0a - r) & 1023;
        int da = (jra < 1024 - jra) ? jra : 1024 - jra;
        tva[r] = (float)Tb[l16 * TSTR + da];
        int jrb = (j0b - r) & 1023;
        int db = (jrb < 1024 - jrb) ? jrb : 1024 - jrb;
        tvb[r] = (float)Tb[(16 + l16) * TSTR + db];
      }
      f32x4 ca = {0.f, 0.f, 0.f, 0.f};
      ca = __builtin_amdgcn_mfma_f32_16x16x32_f16(c0, qa0, ca, 0, 0, 0);
      ca = __builtin_amdgcn_mfma_f32_16x16x32_f16(c1, qa1, ca, 0, 0, 0);
      f32x4 cb = {0.f, 0.f, 0.f, 0.f};
      cb = __builtin_amdgcn_mfma_f32_16x16x32_f16(c0, qb0, cb, 0, 0, 0);
      cb = __builtin_amdgcn_mfma_f32_16x16x32_f16(c1, qb1, cb, 0, 0, 0);
      f16x4 pva, pvb;
      #pragma unroll
      for (int r = 0; r < 4; ++r) {
        float sa = fmaf(ca[r], 0.125f, tva[r]);
        float pa = __expf(sa);
        pva[r] = (f16)pa; psa += pa;
        float sb = fmaf(cb[r], 0.125f, tvb[r]);
        float pb = __expf(sb);
        pvb[r] = (f16)pb; psb += pb;
      }
      *(f16x4*)(Pf + l16 * PROW + kb_) = pva;
      *(f16x4*)(Pf + (16 + l16) * PROW + kb_) = pvb;
    }
    psa += __shfl_xor(psa, 16); psa += __shfl_xor(psa, 32);
    psb += __shfl_xor(psb, 16); psb += __shfl_xor(psb, 32);
    if (quad == 0) {
      lsw[w][l16] = psa;
      lsw[w][16 + l16] = psb;
    }
  }
  // circular pad: Pf[q][1024..1031] = Pf[q][0..7] (wave 0 wrote cols 0..15 at kc=0)
  if (w == 0 && lane < 32)
    *(f16x8*)(Pf + lane * PROW + 1024) = *(const f16x8*)(Pf + lane * PROW);

  // Phase B V prefetch: all 4 iters, issued before barrier 2 (independent of Pf)
  const f16* vtp = Vt + ((size_t)((b * HH + h) * HD) + wd * 16 + l16) * SS
                      + wh * 256 + quad * 8;
  f16x8 v0[4], v1[4];
  #pragma unroll
  for (int t = 0; t < 4; ++t) {
    v0[t] = *(const f16x8*)(vtp + t * 64);
    v1[t] = *(const f16x8*)(vtp + t * 64 + 32);
  }
  __syncthreads();   // barrier 2: Pf + pad + lsw ready

  // ---- Phase B: co = P[., k-quarter] . V[k-quarter, d-group], both subtiles ----
  f32x4 coa = {0.f, 0.f, 0.f, 0.f};
  f32x4 cob = {0.f, 0.f, 0.f, 0.f};
  {
    #pragma unroll
    for (int kc = 0; kc < 4; ++kc) {
      const int jb = wh * 256 + kc * 64 + quad * 8;
      f16x8 ap0 = *(const f16x8*)(Pf + l16 * PROW + jb);
      f16x8 ap1 = *(const f16x8*)(Pf + l16 * PROW + jb + 32);
      coa = __builtin_amdgcn_mfma_f32_16x16x32_f16(ap0, v0[kc], coa, 0, 0, 0);
      coa = __builtin_amdgcn_mfma_f32_16x16x32_f16(ap1, v1[kc], coa, 0, 0, 0);
      f16x8 bp0 = *(const f16x8*)(Pf + (16 + l16) * PROW + jb);
      f16x8 bp1 = *(const f16x8*)(Pf + (16 + l16) * PROW + jb + 32);
      cob = __builtin_amdgcn_mfma_f32_16x16x32_f16(bp0, v0[kc], cob, 0, 0, 0);
      cob = __builtin_amdgcn_mfma_f32_16x16x32_f16(bp1, v1[kc], cob, 0, 0, 0);
    }
  }

  // Wrelv Rv prefetch: both iters issued here, hidden under Phase W compute
  const f16* rvp = Rvt + ((size_t)(wd * 16 + l16)) * RVSTR + wh * 128 + quad * 8;
  f16x8 r0[2], r1[2];
  #pragma unroll
  for (int t = 0; t < 2; ++t) {
    r0[t] = *(const f16x8*)(rvp + t * 64);
    r1[t] = *(const f16x8*)(rvp + t * 64 + 32);
  }

  // ---- Phase W (b128 + funnel): 2048 (row, 8-dist-group) tasks / 1024 threads ----
  #pragma unroll
  for (int it = 0; it < 2; ++it) {
    const int flat = it * 1024 + tid;  // whole wave shares one row ql
    const int ql = flat >> 6;          // 0..31, wave-uniform
    const int gg = flat & 63;          // dist group: dists gg*8 .. gg*8+7
    const int qq = q0 + ql;
    const f16* rowp = Pf + ql * PROW;
    const int sp = qq & 7;             // wave-uniform shift
    const int bp = (qq + 8 * gg) & 1023;
    const f16* app = rowp + (bp - sp);
    u32x4 pA = *(const u32x4*)(app);
    u32x4 pB = *(const u32x4*)(app + 8);
    const int sm = (qq + 1) & 7;       // wave-uniform shift
    const int bm = (qq - 8 * gg - 7) & 1023;
    const f16* apm = rowp + (bm - sm);
    u32x4 mA = *(const u32x4*)(apm);
    u32x4 mB = *(const u32x4*)(apm + 8);
    f16x8 pp = funnel8(pA, pB, sp >> 1, (unsigned)((sp & 1) * 16));
    f16x8 mw = funnel8(mA, mB, sm >> 1, (unsigned)((sm & 1) * 16));
    f16x8 rm = rev8(mw);               // rm[j] = P[(qq - 8*gg - j) & 1023]
    f16x8 wv = rm + pp;
    if (gg == 0) wv[0] = rm[0];        // dist 0: single term P[q]
    *(f16x8*)(Tb + ql * TSTR + gg * 8) = wv;
  }
  if (tid < 32)                        // dist 512: single term P[(q+512) mod S]
    w512[tid] = (float)Pf[tid * PROW + ((q0 + tid + 512) & 1023)];
  __syncthreads();   // barrier 3: W table ready (drains Rv prefetch too)

  // ---- Phase Wrelv: co += W[., dist-quarter] . Rvt[dist-quarter, d-group] ----
  {
    #pragma unroll
    for (int cc = 0; cc < 2; ++cc) {
      const int jb = wh * 128 + cc * 64 + quad * 8;
      f16x8 aw0 = *(const f16x8*)(Tb + l16 * TSTR + jb);
      f16x8 aw1 = *(const f16x8*)(Tb + l16 * TSTR + jb + 32);
      coa = __builtin_amdgcn_mfma_f32_16x16x32_f16(aw0, r0[cc], coa, 0, 0, 0);
      coa = __builtin_amdgcn_mfma_f32_16x16x32_f16(aw1, r1[cc], coa, 0, 0, 0);
      f16x8 bw0 = *(const f16x8*)(Tb + (16 + l16) * TSTR + jb);
      f16x8 bw1 = *(const f16x8*)(Tb + (16 + l16) * TSTR + jb + 32);
      cob = __builtin_amdgcn_mfma_f32_16x16x32_f16(bw0, r0[cc], cob, 0, 0, 0);
      cob = __builtin_amdgcn_mfma_f32_16x16x32_f16(bw1, r1[cc], cob, 0, 0, 0);
    }
  }

  // ---- 4-way partial reduction through Pf (dead since barrier 3) ----
  if (wh > 0) {
    float* st = (float*)Pf + ((size_t)(((wh - 1) * 4 + wd) * 64 + lane)) * 8;
    *(f32x4*)(st) = coa;
    *(f32x4*)(st + 4) = cob;
  }
  __syncthreads();   // barrier 4: partials staged
  if (wh == 0) {
    #pragma unroll
    for (int p = 0; p < 3; ++p) {
      const float* st = (const float*)Pf + ((size_t)((p * 4 + wd) * 64 + lane)) * 8;
      coa += *(const f32x4*)(st);
      cob += *(const f32x4*)(st + 4);
    }
    // ---- finalize: dist-512 rel_v term + normalize + store, both subtiles ----
    const int d = wd * 16 + l16;
    const float rv512 = Rvg[512 * HD + d];
    #pragma unroll
    for (int r = 0; r < 4; ++r) {
      int ql = quad * 4 + r;
      float la = 0.f, lb = 0.f;
      #pragma unroll
      for (int j = 0; j < 16; ++j) { la += lsw[j][ql]; lb += lsw[j][16 + ql]; }
      float oa = coa[r] + w512[ql] * rv512;
      float ob = cob[r] + w512[16 + ql] * rv512;
      Out[((size_t)(b * SS + q0 + ql)) * DD + h * HD + d] = oa / la;
      Out[((size_t)(b * SS + q0 + 16 + ql)) * DD + h * HD + d] = ob / lb;
    }
  }
}

// ---- fallback (R2-style, used only if ws_size is tiny) ----
#define FPSTR 1032
#define FVSTR 68
#define FQPB 16
__global__ __launch_bounds__(256, 2)
void circ_attn_mfma(const float* __restrict__ Qg, const float* __restrict__ Kg,
                    const float* __restrict__ Vg, const float* __restrict__ Rkg,
                    const float* __restrict__ Rvg, float* __restrict__ Out) {
  __shared__ __align__(16) f16 Pf[FQPB * FPSTR];
  __shared__ __align__(16) f16 Tb[FQPB * TSTR];
  __shared__ __align__(16) f16 Sb[64 * KSTR];
  __shared__ __align__(16) f16 Qb[FQPB * KSTR];
  __shared__ float lsw[4][16];
  const int bid = blockIdx.x;
  const int b = bid >> 10, h = (bid >> 6) & 15, q0 = (bid & 63) * FQPB;
  const int tid = threadIdx.x, w = tid >> 6, lane = tid & 63;
  const int quad = lane >> 4, l16 = lane & 15;
  auto stage64 = [&](const float* src, int rstride, f16* dst, int dstr) {
    #pragma unroll
    for (int jj = 0; jj < 4; ++jj) {
      int i = jj * 256 + tid;
      int r = i >> 4, c = (i & 15) << 2;
      float4 v = *(const float4*)(src + (size_t)r * rstride + c);
      f16x4 hv; hv[0] = (f16)v.x; hv[1] = (f16)v.y; hv[2] = (f16)v.z; hv[3] = (f16)v.w;
      *(f16x4*)(dst + r * dstr + c) = hv;
    }
  };
  {
    int r = tid >> 4, c = (tid & 15) << 2;
    float4 v = *(const float4*)(Qg + (size_t)(b * SS + q0 + r) * DD + h * HD + c);
    f16x4 hv; hv[0] = (f16)v.x; hv[1] = (f16)v.y; hv[2] = (f16)v.z; hv[3] = (f16)v.w;
    *(f16x4*)(Qb + r * KSTR + c) = hv;
  }
  __syncthreads();
  const f16x8 qf0 = *(const f16x8*)(Qb + l16 * KSTR + quad * 8);
  const f16x8 qf1 = *(const f16x8*)(Qb + l16 * KSTR + 32 + quad * 8);
  #pragma unroll 1
  for (int cc = 0; cc < 8; ++cc) {
    stage64(Rkg + (size_t)(cc * 64) * HD, HD, Sb, KSTR);
    __syncthreads();
    f16x8 rk0 = *(const f16x8*)(Sb + (w * 16 + l16) * KSTR + quad * 8);
    f16x8 rk1 = *(const f16x8*)(Sb + (w * 16 + l16) * KSTR + 32 + quad * 8);
    f32x4 c = {0.f, 0.f, 0.f, 0.f};
    c = __builtin_amdgcn_mfma_f32_16x16x32_f16(qf0, rk0, c, 0, 0, 0);
    c = __builtin_amdgcn_mfma_f32_16x16x32_f16(qf1, rk1, c, 0, 0, 0);
    const int dbase = cc * 64 + w * 16 + l16;
    #pragma unroll
    for (int r = 0; r < 4; ++r) Tb[(quad * 4 + r) * TSTR + dbase] = (f16)c[r];
    __syncthreads();
  }
  if (w == 0) {
    float t = 0.f;
    #pragma unroll
    for (int i = 0; i < 16; ++i)
      t += (float)Qb[l16 * KSTR + quad * 16 + i] * Rkg[512 * HD + quad * 16 + i];
    t += __shfl_xor(t, 16); t += __shfl_xor(t, 32);
    if (quad == 0) Tb[l16 * TSTR + 512] = (f16)t;
  }
  float psum = 0.f;
  #pragma unroll 1
  for (int kc = 0; kc < 16; ++kc) {
    stage64(Kg + (size_t)(b * SS + kc * 64) * DD + h * HD, DD, Sb, KSTR);
    __syncthreads();
    f16x8 ka0 = *(const f16x8*)(Sb + (w * 16 + l16) * KSTR + quad * 8);
    f16x8 ka1 = *(const f16x8*)(Sb + (w * 16 + l16) * KSTR + 32 + quad * 8);
    f32x4 c = {0.f, 0.f, 0.f, 0.f};
    c = __builtin_amdgcn_mfma_f32_16x16x32_f16(ka0, qf0, c, 0, 0, 0);
    c = __builtin_amdgcn_mfma_f32_16x16x32_f16(ka1, qf1, c, 0, 0, 0);
    const int kb = kc * 64 + w * 16 + quad * 4;
    const int q = q0 + l16;
    f16x4 pv;
    #pragma unroll
    for (int r = 0; r < 4; ++r) {
      int key = kb + r;
      int j = (q - key) & 1023;
      int dist = (j < 1024 - j) ? j : 1024 - j;
      float s = c[r] * 0.125f + (float)Tb[l16 * TSTR + dist];
      float p = __expf(s);
      pv[r] = (f16)p;
      psum += p;
    }
    *(f16x4*)(Pf + l16 * FPSTR + kb) = pv;
    __syncthreads();
  }
  psum += __shfl_xor(psum, 16); psum += __shfl_xor(psum, 32);
  if (quad == 0) lsw[w][l16] = psum;
  f32x4 co = {0.f, 0.f, 0.f, 0.f};
  const int d = w * 16 + l16;
  #pragma unroll 1
  for (int kc = 0; kc < 16; ++kc) {
    stage64(Vg + (size_t)(b * SS + kc * 64) * DD + h * HD, DD, Sb, FVSTR);
    __syncthreads();
    #pragma unroll
    for (int kd = 0; kd < 2; ++kd) {
      f16x8 bv;
      #pragma unroll
      for (int j = 0; j < 8; ++j) bv[j] = Sb[(kd * 32 + quad * 8 + j) * FVSTR + d];
      f16x8 ap = *(const f16x8*)(Pf + l16 * FPSTR + kc * 64 + kd * 32 + quad * 8);
      co = __builtin_amdgcn_mfma_f32_16x16x32_f16(ap, bv, co, 0, 0, 0);
    }
    __syncthreads();
  }
  #pragma unroll 1
  for (int i = tid; i < FQPB * 513; i += 256) {
    int ql = i / 513, dist = i - ql * 513, q = q0 + ql;
    int k1 = (q - dist) & 1023;
    float wv = (float)Pf[ql * FPSTR + k1];
    if (dist != 0 && dist != 512) wv += (float)Pf[ql * FPSTR + ((q + dist) & 1023)];
    Tb[ql * TSTR + dist] = (f16)wv;
  }
  __syncthreads();
  #pragma unroll 1
  for (int cc = 0; cc < 8; ++cc) {
    stage64(Rvg + (size_t)(cc * 64) * HD, HD, Sb, FVSTR);
    __syncthreads();
    #pragma unroll
    for (int kd = 0; kd < 2; ++kd) {
      f16x8 bv;
      #pragma unroll
      for (int j = 0; j < 8; ++j) bv[j] = Sb[(kd * 32 + quad * 8 + j) * FVSTR + d];
      f16x8 aw = *(const f16x8*)(Tb + l16 * TSTR + cc * 64 + kd * 32 + quad * 8);
      co = __builtin_amdgcn_mfma_f32_16x16x32_f16(aw, bv, co, 0, 0, 0);
    }
    __syncthreads();
  }
  const float rv512 = Rvg[512 * HD + d];
  #pragma unroll
  for (int r = 0; r < 4; ++r) {
    int ql = quad * 4 + r;
    float l = lsw[0][ql] + lsw[1][ql] + lsw[2][ql] + lsw[3][ql];
    float o = co[r] + (float)Tb[ql * TSTR + 512] * rv512;
    Out[(size_t)(b * SS + q0 + ql) * DD + h * HD + d] = o / l;
  }
}

extern "C" void kernel_launch(void* const* d_in, const int* in_sizes, int n_in,
                              void* d_out, int out_size, void* d_ws, size_t ws_size,
                              hipStream_t stream) {
  const float* q  = (const float*)d_in[0];
  const float* k  = (const float*)d_in[1];
  const float* v  = (const float*)d_in[2];
  const float* rk = (const float*)d_in[3];
  const float* rv = (const float*)d_in[4];
  float* out = (float*)d_out;
  const int nblocks = BB * HH * (SS / QPB);  // 4096
  f16* vt  = (f16*)d_ws;
  f16* rvt = vt + VT_ELEMS;
  f16* rkt = rvt + RVT_ELEMS;
  f16* kt  = rkt + RKT_ELEMS;
  if (ws_size >= WS_FULL) {
    prep_kernel<<<dim3(2058 + 2048), dim3(256), 0, stream>>>(v, rv, k, rk, vt, rvt, rkt, kt);
    circ_attn_v10<true><<<dim3(nblocks), dim3(1024), 0, stream>>>(
        q, k, kt, rkt, rk, rv, vt, rvt, out);
  } else if (ws_size >= WS_PART) {
    prep_kernel<<<dim3(2058), dim3(256), 0, stream>>>(v, rv, k, rk, vt, rvt, rkt, kt);
    circ_attn_v10<false><<<dim3(nblocks), dim3(1024), 0, stream>>>(
        q, k, kt, rkt, rk, rv, vt, rvt, out);
  } else {
    circ_attn_mfma<<<dim3(8192), dim3(256), 0, stream>>>(q, k, v, rk, rv, out);
  }
}

// Round 7
// 339.751 us; speedup vs baseline: 1.7947x; 1.1420x over previous
//
#include <hip/hip_runtime.h>

typedef _Float16 f16;
typedef __attribute__((ext_vector_type(4))) _Float16 f16x4;
typedef __attribute__((ext_vector_type(8))) _Float16 f16x8;
typedef __attribute__((ext_vector_type(4))) float f32x4;
typedef __attribute__((ext_vector_type(4))) unsigned int u32x4;

#define BB 8
#define SS 1024
#define DD 1024
#define HH 16
#define HD 64
#define QPB 32      // q-rows per block (2 subtiles of 16) -- halves stream traffic
#define PROW 1040   // Pf row len (f16): cols 0..1023 + 8 circular pad, 16B-aligned
#define TSTR 520    // T/W table row stride (f16)
#define KSTR 72     // LDS staging stride (Q tile here; prep kernel too)
#define RVSTR 520   // Rvt global row stride (f16)

#define VT_ELEMS  ((size_t)BB * HH * HD * SS)   // 8,388,608
#define RVT_ELEMS ((size_t)HD * RVSTR)          // 33,280
#define RKT_ELEMS ((size_t)513 * HD)            // 32,832
#define KT_ELEMS  ((size_t)BB * HH * SS * HD)   // 8,388,608
#define WS_PART ((VT_ELEMS + RVT_ELEMS + RKT_ELEMS) * 2)
#define WS_FULL ((VT_ELEMS + RVT_ELEMS + RKT_ELEMS + KT_ELEMS) * 2)

__device__ inline f16x8 cvt16(float4 a, float4 b) {
  f16x8 h;
  h[0] = (f16)a.x; h[1] = (f16)a.y; h[2] = (f16)a.z; h[3] = (f16)a.w;
  h[4] = (f16)b.x; h[5] = (f16)b.y; h[6] = (f16)b.z; h[7] = (f16)b.w;
  return h;
}

// funnel-extract 8 f16 starting at element s (0..7) of a 16-f16 window {lo, hi}
__device__ inline f16x8 funnel8(u32x4 lo, u32x4 hi, int sh, unsigned lob) {
  unsigned e0 = (sh & 1) ? lo.y : lo.x;
  unsigned e1 = (sh & 1) ? lo.z : lo.y;
  unsigned e2 = (sh & 1) ? lo.w : lo.z;
  unsigned e3 = (sh & 1) ? hi.x : lo.w;
  unsigned e4 = (sh & 1) ? hi.y : hi.x;
  unsigned f0 = (sh & 2) ? e2 : e0;
  unsigned f1 = (sh & 2) ? e3 : e1;
  unsigned f2 = (sh & 2) ? e4 : e2;
  unsigned f3 = (sh & 2) ? ((sh & 1) ? hi.z : hi.y) : e3;
  unsigned f4 = (sh & 2) ? ((sh & 1) ? hi.w : hi.z) : e4;
  union { u32x4 u; f16x8 h; } o;
  o.u.x = __builtin_amdgcn_alignbit(f1, f0, lob);
  o.u.y = __builtin_amdgcn_alignbit(f2, f1, lob);
  o.u.z = __builtin_amdgcn_alignbit(f3, f2, lob);
  o.u.w = __builtin_amdgcn_alignbit(f4, f3, lob);
  return o.h;
}

// reverse 8 f16 in-register
__device__ inline f16x8 rev8(f16x8 v) {
  union { u32x4 u; f16x8 h; } i, o;
  i.h = v;
  o.u.x = __builtin_amdgcn_alignbit(i.u.w, i.u.w, 16);
  o.u.y = __builtin_amdgcn_alignbit(i.u.z, i.u.z, 16);
  o.u.z = __builtin_amdgcn_alignbit(i.u.y, i.u.y, 16);
  o.u.w = __builtin_amdgcn_alignbit(i.u.x, i.u.x, 16);
  return o.h;
}

// ---- prep: Vt[b][h][d][s], Rvt[d][dist] (transposes), Kt[b][h][s][d], Rkt f16 casts ----
__global__ __launch_bounds__(256, 2)
void prep_kernel(const float* __restrict__ Vg, const float* __restrict__ Rvg,
                 const float* __restrict__ Kg, const float* __restrict__ Rkg,
                 f16* __restrict__ Vt, f16* __restrict__ Rvt,
                 f16* __restrict__ Rkt, f16* __restrict__ Kt) {
  __shared__ __align__(16) f16 Tt[64 * KSTR];
  const int tid = threadIdx.x;
  const int bid = blockIdx.x;

  if (bid < 2056) {  // transpose sections (V, Rv)
    const int sr = tid >> 2, cs = (tid & 3) * 16;
    const float* src;
    int srcstride;
    f16* dst;
    int dststride, dstcol;
    if (bid < 2048) {
      int b = bid >> 8, h = (bid >> 4) & 15, tc = bid & 15;
      src = Vg + ((size_t)(b * SS + tc * 64)) * DD + h * HD;
      srcstride = DD;
      dst = Vt + ((size_t)((b * HH + h) * HD)) * SS;
      dststride = SS; dstcol = tc * 64;
    } else {
      int cc = bid - 2048;                       // 0..7, dists 0..511
      src = Rvg + ((size_t)(cc * 64)) * HD;
      srcstride = HD;
      dst = Rvt;
      dststride = RVSTR; dstcol = cc * 64;
    }
    {
      const float* s = src + (size_t)sr * srcstride + cs;
      float4 v0 = *(const float4*)(s);
      float4 v1 = *(const float4*)(s + 4);
      float4 v2 = *(const float4*)(s + 8);
      float4 v3 = *(const float4*)(s + 12);
      *(f16x8*)(Tt + sr * KSTR + cs) = cvt16(v0, v1);
      *(f16x8*)(Tt + sr * KSTR + cs + 8) = cvt16(v2, v3);
    }
    __syncthreads();
    {
      f16x8 o0, o1;
      #pragma unroll
      for (int i = 0; i < 8; ++i) o0[i] = Tt[(cs + i) * KSTR + sr];
      #pragma unroll
      for (int i = 0; i < 8; ++i) o1[i] = Tt[(cs + 8 + i) * KSTR + sr];
      f16* o = dst + (size_t)sr * dststride + dstcol + cs;
      *(f16x8*)(o) = o0;
      *(f16x8*)(o + 8) = o1;
    }
  } else if (bid < 2058) {  // Rk cast: 513*64 = 32832 elems, 2 blocks
    const int base = (bid - 2056) * 16416;
    for (int j = tid; j < 16416; j += 256)
      Rkt[base + j] = (f16)Rkg[base + j];
  } else {
    // K cast -> Kt[b][h][s][d]
    const int n = bid - 2058;
    #pragma unroll
    for (int jj = 0; jj < 4; ++jj) {
      int o4 = n * 1024 + jj * 256 + tid;
      int d4 = o4 & 15;
      int s  = (o4 >> 4) & 1023;
      int bh = o4 >> 14;                 // 0..127
      int b = bh >> 4, h = bh & 15;
      float4 v = *(const float4*)(Kg + ((size_t)(b * SS + s)) * DD + h * HD + d4 * 4);
      f16x4 hv; hv[0] = (f16)v.x; hv[1] = (f16)v.y; hv[2] = (f16)v.z; hv[3] = (f16)v.w;
      *(f16x4*)(Kt + (size_t)o4 * 4) = hv;
    }
  }
}

// ---- main v11: v10 + Q staged through LDS (kills the 16x-duplicated Q global
// reads: 128 KB -> 32 KB of per-block L2 requests, -18% total requests).
// Everything else identical to v10. LDS 107 KB -> 1 block/CU (16 waves).
template <bool KT16>
__global__ __launch_bounds__(1024, 4)
void circ_attn_v11(const float* __restrict__ Qg, const float* __restrict__ Kg,
                   const f16* __restrict__ Kt, const f16* __restrict__ Rkt,
                   const float* __restrict__ Rkg, const float* __restrict__ Rvg,
                   const f16* __restrict__ Vt, const f16* __restrict__ Rvt,
                   float* __restrict__ Out) {
  __shared__ __align__(16) f16 Pf[QPB * PROW];    // 66,560 B
  __shared__ __align__(16) f16 Tb[QPB * TSTR];    // 33,280 B (T table, then W table)
  __shared__ __align__(16) f16 Qls[QPB * KSTR];   // 4,608 B (f16 Q tile)
  __shared__ float lsw[16][32];                   // 2 KB
  __shared__ float w512[32];

  // XCD swizzle: all 32 q-blocks of one (b,h) land on XCD (i & 7)
  const int i = blockIdx.x;
  const int g = ((i >> 8) << 3) | (i & 7);   // (b,h) group 0..127
  const int m = (i >> 3) & 31;               // q-block 0..31
  const int b = g >> 4;
  const int h = g & 15;
  const int q0 = m * QPB;

  const int tid = threadIdx.x;
  const int w = tid >> 6;        // 0..15
  const int lane = tid & 63;
  const int quad = lane >> 4;
  const int l16 = lane & 15;
  const int wd = w & 3;          // output d-group 0..3
  const int wh = w >> 2;         // k-quarter / dist-quarter 0..3

  // ---- stage Q tile once: 32 rows x 64 cols fp32 -> f16 LDS (waves 0-3 only) ----
  if (tid < 256) {
    const int r = tid >> 3;            // 0..31
    const int cg = tid & 7;            // 8-col group
    const float* qsrc = Qg + ((size_t)(b * SS + q0 + r)) * DD + h * HD + cg * 8;
    float4 u0 = *(const float4*)(qsrc);
    float4 u1 = *(const float4*)(qsrc + 4);
    *(f16x8*)(Qls + r * KSTR + cg * 8) = cvt16(u0, u1);
  }
  __syncthreads();   // barrier 0: Q tile ready

  // ---- Q fragments for BOTH subtiles from LDS (identical values for all waves) ----
  f16x8 qa0, qa1, qb0, qb1;
  {
    const f16* qp = Qls + l16 * KSTR + quad * 8;
    qa0 = *(const f16x8*)(qp);
    qa1 = *(const f16x8*)(qp + 32);
    const f16* qp2 = Qls + (16 + l16) * KSTR + quad * 8;
    qb0 = *(const f16x8*)(qp2);
    qb1 = *(const f16x8*)(qp2 + 32);
  }

  // ---- Phase T: T[q][dist] for 32 rows; wave w covers dists cc*256 + w*16 + l16 ----
  {
    const f16* rkp = Rkt + ((size_t)(w * 16 + l16)) * HD + quad * 8;
    f16x8 t0[2], t1[2];
    #pragma unroll
    for (int t = 0; t < 2; ++t) {
      const f16* np = rkp + (size_t)t * 256 * HD;
      t0[t] = *(const f16x8*)(np);
      t1[t] = *(const f16x8*)(np + 32);
    }
    #pragma unroll
    for (int cc = 0; cc < 2; ++cc) {
      f32x4 ca = {0.f, 0.f, 0.f, 0.f};
      ca = __builtin_amdgcn_mfma_f32_16x16x32_f16(qa0, t0[cc], ca, 0, 0, 0);
      ca = __builtin_amdgcn_mfma_f32_16x16x32_f16(qa1, t1[cc], ca, 0, 0, 0);
      f32x4 cb = {0.f, 0.f, 0.f, 0.f};
      cb = __builtin_amdgcn_mfma_f32_16x16x32_f16(qb0, t0[cc], cb, 0, 0, 0);
      cb = __builtin_amdgcn_mfma_f32_16x16x32_f16(qb1, t1[cc], cb, 0, 0, 0);
      const int dbase = cc * 256 + w * 16 + l16;
      #pragma unroll
      for (int r = 0; r < 4; ++r) {
        Tb[(quad * 4 + r) * TSTR + dbase] = (f16)ca[r];
        Tb[(16 + quad * 4 + r) * TSTR + dbase] = (f16)cb[r];
      }
    }
  }
  // dist 512 (wave 0 only, f32 path) for both subtiles
  if (w == 0) {
    const float* rk = Rkg + 512 * HD;
    float ta = 0.f, tb = 0.f;
    #pragma unroll
    for (int j = 0; j < 8; ++j) {
      float rkv0 = rk[quad * 8 + j], rkv1 = rk[32 + quad * 8 + j];
      ta += (float)qa0[j] * rkv0 + (float)qa1[j] * rkv1;
      tb += (float)qb0[j] * rkv0 + (float)qb1[j] * rkv1;
    }
    ta += __shfl_xor(ta, 16); ta += __shfl_xor(ta, 32);
    tb += __shfl_xor(tb, 16); tb += __shfl_xor(tb, 32);
    if (quad == 0) {
      Tb[l16 * TSTR + 512] = (f16)ta;
      Tb[(16 + l16) * TSTR + 512] = (f16)tb;
    }
  }

  // Phase A K prefetch: all 4 iters, issued before barrier 1 (independent of Tb)
  const f16* kp16 = KT16 ?
      (Kt + (((size_t)(b * HH + h) << 10) + w * 16 + l16) * HD + quad * 8) : nullptr;
  const float* kp32 = KT16 ? nullptr :
      (Kg + ((size_t)(b * SS + w * 16 + l16)) * DD + h * HD + quad * 8);
  f16x8 k0[4], k1[4];
  float4 f0, f1, f2, f3;
  if (KT16) {
    #pragma unroll
    for (int t = 0; t < 4; ++t) {
      const f16* np = kp16 + (size_t)t * 256 * HD;
      k0[t] = *(const f16x8*)(np);
      k1[t] = *(const f16x8*)(np + 32);
    }
  } else {
    f0 = *(const float4*)(kp32);
    f1 = *(const float4*)(kp32 + 4);
    f2 = *(const float4*)(kp32 + 32);
    f3 = *(const float4*)(kp32 + 36);
  }
  __syncthreads();   // barrier 1: Tb(T) ready

  // ---- Phase A: S^T = K . Q^T for both subtiles; wave w covers k = kc*256+w*16+.. ----
  {
    float psa = 0.f, psb = 0.f;
    #pragma unroll
    for (int kc = 0; kc < 4; ++kc) {
      f16x8 c0, c1;
      if (KT16) {
        c0 = k0[kc]; c1 = k1[kc];
      } else {
        c0 = cvt16(f0, f1); c1 = cvt16(f2, f3);
        if (kc < 3) {
          const float* s = kp32 + (size_t)(kc + 1) * 256 * DD;
          f0 = *(const float4*)(s);      f1 = *(const float4*)(s + 4);
          f2 = *(const float4*)(s + 32); f3 = *(const float4*)(s + 36);
        }
      }
      const int kb_ = kc * 256 + w * 16 + quad * 4;
      // bias gathers for both subtiles (independent of MFMA result)
      const int j0a = ((q0 + l16) - kb_) & 1023;
      const int j0b = (j0a + 16) & 1023;
      float tva[4], tvb[4];
      #pragma unroll
      for (int r = 0; r < 4; ++r) {
        int jra = (j0a - r) & 1023;
        int da = (jra < 1024 - jra) ? jra : 1024 - jra;
        tva[r] = (float)Tb[l16 * TSTR + da];
        int jrb = (j0b - r) & 1023;
        int db = (jrb < 1024 - jrb) ? jrb : 1024 - jrb;
        tvb[r] = (float)Tb[(16 + l16) * TSTR + db];
      }
      f32x4 ca = {0.f, 0.f, 0.f, 0.f};
      ca = __builtin_amdgcn_mfma_f32_16x16x32_f16(c0, qa0, ca, 0, 0, 0);
      ca = __builtin_amdgcn_mfma_f32_16x16x32_f16(c1, qa1, ca, 0, 0, 0);
      f32x4 cb = {0.f, 0.f, 0.f, 0.f};
      cb = __builtin_amdgcn_mfma_f32_16x16x32_f16(c0, qb0, cb, 0, 0, 0);
      cb = __builtin_amdgcn_mfma_f32_16x16x32_f16(c1, qb1, cb, 0, 0, 0);
      f16x4 pva, pvb;
      #pragma unroll
      for (int r = 0; r < 4; ++r) {
        float sa = fmaf(ca[r], 0.125f, tva[r]);
        float pa = __expf(sa);
        pva[r] = (f16)pa; psa += pa;
        float sb = fmaf(cb[r], 0.125f, tvb[r]);
        float pb = __expf(sb);
        pvb[r] = (f16)pb; psb += pb;
      }
      *(f16x4*)(Pf + l16 * PROW + kb_) = pva;
      *(f16x4*)(Pf + (16 + l16) * PROW + kb_) = pvb;
    }
    psa += __shfl_xor(psa, 16); psa += __shfl_xor(psa, 32);
    psb += __shfl_xor(psb, 16); psb += __shfl_xor(psb, 32);
    if (quad == 0) {
      lsw[w][l16] = psa;
      lsw[w][16 + l16] = psb;
    }
  }
  // circular pad: Pf[q][1024..1031] = Pf[q][0..7] (wave 0 wrote cols 0..15 at kc=0)
  if (w == 0 && lane < 32)
    *(f16x8*)(Pf + lane * PROW + 1024) = *(const f16x8*)(Pf + lane * PROW);

  // Phase B V prefetch: all 4 iters, issued before barrier 2 (independent of Pf)
  const f16* vtp = Vt + ((size_t)((b * HH + h) * HD) + wd * 16 + l16) * SS
                      + wh * 256 + quad * 8;
  f16x8 v0[4], v1[4];
  #pragma unroll
  for (int t = 0; t < 4; ++t) {
    v0[t] = *(const f16x8*)(vtp + t * 64);
    v1[t] = *(const f16x8*)(vtp + t * 64 + 32);
  }
  __syncthreads();   // barrier 2: Pf + pad + lsw ready

  // ---- Phase B: co = P[., k-quarter] . V[k-quarter, d-group], both subtiles ----
  f32x4 coa = {0.f, 0.f, 0.f, 0.f};
  f32x4 cob = {0.f, 0.f, 0.f, 0.f};
  {
    #pragma unroll
    for (int kc = 0; kc < 4; ++kc) {
      const int jb = wh * 256 + kc * 64 + quad * 8;
      f16x8 ap0 = *(const f16x8*)(Pf + l16 * PROW + jb);
      f16x8 ap1 = *(const f16x8*)(Pf + l16 * PROW + jb + 32);
      coa = __builtin_amdgcn_mfma_f32_16x16x32_f16(ap0, v0[kc], coa, 0, 0, 0);
      coa = __builtin_amdgcn_mfma_f32_16x16x32_f16(ap1, v1[kc], coa, 0, 0, 0);
      f16x8 bp0 = *(const f16x8*)(Pf + (16 + l16) * PROW + jb);
      f16x8 bp1 = *(const f16x8*)(Pf + (16 + l16) * PROW + jb + 32);
      cob = __builtin_amdgcn_mfma_f32_16x16x32_f16(bp0, v0[kc], cob, 0, 0, 0);
      cob = __builtin_amdgcn_mfma_f32_16x16x32_f16(bp1, v1[kc], cob, 0, 0, 0);
    }
  }

  // Wrelv Rv prefetch: both iters issued here, hidden under Phase W compute
  const f16* rvp = Rvt + ((size_t)(wd * 16 + l16)) * RVSTR + wh * 128 + quad * 8;
  f16x8 r0[2], r1[2];
  #pragma unroll
  for (int t = 0; t < 2; ++t) {
    r0[t] = *(const f16x8*)(rvp + t * 64);
    r1[t] = *(const f16x8*)(rvp + t * 64 + 32);
  }

  // ---- Phase W (b128 + funnel): 2048 (row, 8-dist-group) tasks / 1024 threads ----
  #pragma unroll
  for (int it = 0; it < 2; ++it) {
    const int flat = it * 1024 + tid;  // whole wave shares one row ql
    const int ql = flat >> 6;          // 0..31, wave-uniform
    const int gg = flat & 63;          // dist group: dists gg*8 .. gg*8+7
    const int qq = q0 + ql;
    const f16* rowp = Pf + ql * PROW;
    const int sp = qq & 7;             // wave-uniform shift
    const int bp = (qq + 8 * gg) & 1023;
    const f16* app = rowp + (bp - sp);
    u32x4 pA = *(const u32x4*)(app);
    u32x4 pB = *(const u32x4*)(app + 8);
    const int sm = (qq + 1) & 7;       // wave-uniform shift
    const int bm = (qq - 8 * gg - 7) & 1023;
    const f16* apm = rowp + (bm - sm);
    u32x4 mA = *(const u32x4*)(apm);
    u32x4 mB = *(const u32x4*)(apm + 8);
    f16x8 pp = funnel8(pA, pB, sp >> 1, (unsigned)((sp & 1) * 16));
    f16x8 mw = funnel8(mA, mB, sm >> 1, (unsigned)((sm & 1) * 16));
    f16x8 rm = rev8(mw);               // rm[j] = P[(qq - 8*gg - j) & 1023]
    f16x8 wv = rm + pp;
    if (gg == 0) wv[0] = rm[0];        // dist 0: single term P[q]
    *(f16x8*)(Tb + ql * TSTR + gg * 8) = wv;
  }
  if (tid < 32)                        // dist 512: single term P[(q+512) mod S]
    w512[tid] = (float)Pf[tid * PROW + ((q0 + tid + 512) & 1023)];
  __syncthreads();   // barrier 3: W table ready (drains Rv prefetch too)

  // ---- Phase Wrelv: co += W[., dist-quarter] . Rvt[dist-quarter, d-group] ----
  {
    #pragma unroll
    for (int cc = 0; cc < 2; ++cc) {
      const int jb = wh * 128 + cc * 64 + quad * 8;
      f16x8 aw0 = *(const f16x8*)(Tb + l16 * TSTR + jb);
      f16x8 aw1 = *(const f16x8*)(Tb + l16 * TSTR + jb + 32);
      coa = __builtin_amdgcn_mfma_f32_16x16x32_f16(aw0, r0[cc], coa, 0, 0, 0);
      coa = __builtin_amdgcn_mfma_f32_16x16x32_f16(aw1, r1[cc], coa, 0, 0, 0);
      f16x8 bw0 = *(const f16x8*)(Tb + (16 + l16) * TSTR + jb);
      f16x8 bw1 = *(const f16x8*)(Tb + (16 + l16) * TSTR + jb + 32);
      cob = __builtin_amdgcn_mfma_f32_16x16x32_f16(bw0, r0[cc], cob, 0, 0, 0);
      cob = __builtin_amdgcn_mfma_f32_16x16x32_f16(bw1, r1[cc], cob, 0, 0, 0);
    }
  }

  // ---- 4-way partial reduction through Pf (dead since barrier 3) ----
  if (wh > 0) {
    float* st = (float*)Pf + ((size_t)(((wh - 1) * 4 + wd) * 64 + lane)) * 8;
    *(f32x4*)(st) = coa;
    *(f32x4*)(st + 4) = cob;
  }
  __syncthreads();   // barrier 4: partials staged
  if (wh == 0) {
    #pragma unroll
    for (int p = 0; p < 3; ++p) {
      const float* st = (const float*)Pf + ((size_t)((p * 4 + wd) * 64 + lane)) * 8;
      coa += *(const f32x4*)(st);
      cob += *(const f32x4*)(st + 4);
    }
    // ---- finalize: dist-512 rel_v term + normalize + store, both subtiles ----
    const int d = wd * 16 + l16;
    const float rv512 = Rvg[512 * HD + d];
    #pragma unroll
    for (int r = 0; r < 4; ++r) {
      int ql = quad * 4 + r;
      float la = 0.f, lb = 0.f;
      #pragma unroll
      for (int j = 0; j < 16; ++j) { la += lsw[j][ql]; lb += lsw[j][16 + ql]; }
      float oa = coa[r] + w512[ql] * rv512;
      float ob = cob[r] + w512[16 + ql] * rv512;
      Out[((size_t)(b * SS + q0 + ql)) * DD + h * HD + d] = oa / la;
      Out[((size_t)(b * SS + q0 + 16 + ql)) * DD + h * HD + d] = ob / lb;
    }
  }
}

// ---- fallback (R2-style, used only if ws_size is tiny) ----
#define FPSTR 1032
#define FVSTR 68
#define FQPB 16
__global__ __launch_bounds__(256, 2)
void circ_attn_mfma(const float* __restrict__ Qg, const float* __restrict__ Kg,
                    const float* __restrict__ Vg, const float* __restrict__ Rkg,
                    const float* __restrict__ Rvg, float* __restrict__ Out) {
  __shared__ __align__(16) f16 Pf[FQPB * FPSTR];
  __shared__ __align__(16) f16 Tb[FQPB * TSTR];
  __shared__ __align__(16) f16 Sb[64 * KSTR];
  __shared__ __align__(16) f16 Qb[FQPB * KSTR];
  __shared__ float lsw[4][16];
  const int bid = blockIdx.x;
  const int b = bid >> 10, h = (bid >> 6) & 15, q0 = (bid & 63) * FQPB;
  const int tid = threadIdx.x, w = tid >> 6, lane = tid & 63;
  const int quad = lane >> 4, l16 = lane & 15;
  auto stage64 = [&](const float* src, int rstride, f16* dst, int dstr) {
    #pragma unroll
    for (int jj = 0; jj < 4; ++jj) {
      int i = jj * 256 + tid;
      int r = i >> 4, c = (i & 15) << 2;
      float4 v = *(const float4*)(src + (size_t)r * rstride + c);
      f16x4 hv; hv[0] = (f16)v.x; hv[1] = (f16)v.y; hv[2] = (f16)v.z; hv[3] = (f16)v.w;
      *(f16x4*)(dst + r * dstr + c) = hv;
    }
  };
  {
    int r = tid >> 4, c = (tid & 15) << 2;
    float4 v = *(const float4*)(Qg + (size_t)(b * SS + q0 + r) * DD + h * HD + c);
    f16x4 hv; hv[0] = (f16)v.x; hv[1] = (f16)v.y; hv[2] = (f16)v.z; hv[3] = (f16)v.w;
    *(f16x4*)(Qb + r * KSTR + c) = hv;
  }
  __syncthreads();
  const f16x8 qf0 = *(const f16x8*)(Qb + l16 * KSTR + quad * 8);
  const f16x8 qf1 = *(const f16x8*)(Qb + l16 * KSTR + 32 + quad * 8);
  #pragma unroll 1
  for (int cc = 0; cc < 8; ++cc) {
    stage64(Rkg + (size_t)(cc * 64) * HD, HD, Sb, KSTR);
    __syncthreads();
    f16x8 rk0 = *(const f16x8*)(Sb + (w * 16 + l16) * KSTR + quad * 8);
    f16x8 rk1 = *(const f16x8*)(Sb + (w * 16 + l16) * KSTR + 32 + quad * 8);
    f32x4 c = {0.f, 0.f, 0.f, 0.f};
    c = __builtin_amdgcn_mfma_f32_16x16x32_f16(qf0, rk0, c, 0, 0, 0);
    c = __builtin_amdgcn_mfma_f32_16x16x32_f16(qf1, rk1, c, 0, 0, 0);
    const int dbase = cc * 64 + w * 16 + l16;
    #pragma unroll
    for (int r = 0; r < 4; ++r) Tb[(quad * 4 + r) * TSTR + dbase] = (f16)c[r];
    __syncthreads();
  }
  if (w == 0) {
    float t = 0.f;
    #pragma unroll
    for (int i = 0; i < 16; ++i)
      t += (float)Qb[l16 * KSTR + quad * 16 + i] * Rkg[512 * HD + quad * 16 + i];
    t += __shfl_xor(t, 16); t += __shfl_xor(t, 32);
    if (quad == 0) Tb[l16 * TSTR + 512] = (f16)t;
  }
  float psum = 0.f;
  #pragma unroll 1
  for (int kc = 0; kc < 16; ++kc) {
    stage64(Kg + (size_t)(b * SS + kc * 64) * DD + h * HD, DD, Sb, KSTR);
    __syncthreads();
    f16x8 ka0 = *(const f16x8*)(Sb + (w * 16 + l16) * KSTR + quad * 8);
    f16x8 ka1 = *(const f16x8*)(Sb + (w * 16 + l16) * KSTR + 32 + quad * 8);
    f32x4 c = {0.f, 0.f, 0.f, 0.f};
    c = __builtin_amdgcn_mfma_f32_16x16x32_f16(ka0, qf0, c, 0, 0, 0);
    c = __builtin_amdgcn_mfma_f32_16x16x32_f16(ka1, qf1, c, 0, 0, 0);
    const int kb = kc * 64 + w * 16 + quad * 4;
    const int q = q0 + l16;
    f16x4 pv;
    #pragma unroll
    for (int r = 0; r < 4; ++r) {
      int key = kb + r;
      int j = (q - key) & 1023;
      int dist = (j < 1024 - j) ? j : 1024 - j;
      float s = c[r] * 0.125f + (float)Tb[l16 * TSTR + dist];
      float p = __expf(s);
      pv[r] = (f16)p;
      psum += p;
    }
    *(f16x4*)(Pf + l16 * FPSTR + kb) = pv;
    __syncthreads();
  }
  psum += __shfl_xor(psum, 16); psum += __shfl_xor(psum, 32);
  if (quad == 0) lsw[w][l16] = psum;
  f32x4 co = {0.f, 0.f, 0.f, 0.f};
  const int d = w * 16 + l16;
  #pragma unroll 1
  for (int kc = 0; kc < 16; ++kc) {
    stage64(Vg + (size_t)(b * SS + kc * 64) * DD + h * HD, DD, Sb, FVSTR);
    __syncthreads();
    #pragma unroll
    for (int kd = 0; kd < 2; ++kd) {
      f16x8 bv;
      #pragma unroll
      for (int j = 0; j < 8; ++j) bv[j] = Sb[(kd * 32 + quad * 8 + j) * FVSTR + d];
      f16x8 ap = *(const f16x8*)(Pf + l16 * FPSTR + kc * 64 + kd * 32 + quad * 8);
      co = __builtin_amdgcn_mfma_f32_16x16x32_f16(ap, bv, co, 0, 0, 0);
    }
    __syncthreads();
  }
  #pragma unroll 1
  for (int i = tid; i < FQPB * 513; i += 256) {
    int ql = i / 513, dist = i - ql * 513, q = q0 + ql;
    int k1 = (q - dist) & 1023;
    float wv = (float)Pf[ql * FPSTR + k1];
    if (dist != 0 && dist != 512) wv += (float)Pf[ql * FPSTR + ((q + dist) & 1023)];
    Tb[ql * TSTR + dist] = (f16)wv;
  }
  __syncthreads();
  #pragma unroll 1
  for (int cc = 0; cc < 8; ++cc) {
    stage64(Rvg + (size_t)(cc * 64) * HD, HD, Sb, FVSTR);
    __syncthreads();
    #pragma unroll
    for (int kd = 0; kd < 2; ++kd) {
      f16x8 bv;
      #pragma unroll
      for (int j = 0; j < 8; ++j) bv[j] = Sb[(kd * 32 + quad * 8 + j) * FVSTR + d];
      f16x8 aw = *(const f16x8*)(Tb + l16 * TSTR + cc * 64 + kd * 32 + quad * 8);
      co = __builtin_amdgcn_mfma_f32_16x16x32_f16(aw, bv, co, 0, 0, 0);
    }
    __syncthreads();
  }
  const float rv512 = Rvg[512 * HD + d];
  #pragma unroll
  for (int r = 0; r < 4; ++r) {
    int ql = quad * 4 + r;
    float l = lsw[0][ql] + lsw[1][ql] + lsw[2][ql] + lsw[3][ql];
    float o = co[r] + (float)Tb[ql * TSTR + 512] * rv512;
    Out[(size_t)(b * SS + q0 + ql) * DD + h * HD + d] = o / l;
  }
}

extern "C" void kernel_launch(void* const* d_in, const int* in_sizes, int n_in,
                              void* d_out, int out_size, void* d_ws, size_t ws_size,
                              hipStream_t stream) {
  const float* q  = (const float*)d_in[0];
  const float* k  = (const float*)d_in[1];
  const float* v  = (const float*)d_in[2];
  const float* rk = (const float*)d_in[3];
  const float* rv = (const float*)d_in[4];
  float* out = (float*)d_out;
  const int nblocks = BB * HH * (SS / QPB);  // 4096
  f16* vt  = (f16*)d_ws;
  f16* rvt = vt + VT_ELEMS;
  f16* rkt = rvt + RVT_ELEMS;
  f16* kt  = rkt + RKT_ELEMS;
  if (ws_size >= WS_FULL) {
    prep_kernel<<<dim3(2058 + 2048), dim3(256), 0, stream>>>(v, rv, k, rk, vt, rvt, rkt, kt);
    circ_attn_v11<true><<<dim3(nblocks), dim3(1024), 0, stream>>>(
        q, k, kt, rkt, rk, rv, vt, rvt, out);
  } else if (ws_size >= WS_PART) {
    prep_kernel<<<dim3(2058), dim3(256), 0, stream>>>(v, rv, k, rk, vt, rvt, rkt, kt);
    circ_attn_v11<false><<<dim3(nblocks), dim3(1024), 0, stream>>>(
        q, k, kt, rkt, rk, rv, vt, rvt, out);
  } else {
    circ_attn_mfma<<<dim3(8192), dim3(256), 0, stream>>>(q, k, v, rk, rv, out);
  }
}